// Round 10
// baseline (214.742 us; speedup 1.0000x reference)
//
#include <hip/hip_runtime.h>
#include <math.h>

// ---------- constants ----------
#define B_  2
#define T_  4096
#define DM  2048
#define H_  16
#define HKV 4
#define DV_ 64
#define MB_ 64
#define LW_ 1024
#define REMOTE 3072     // T - LW
#define NBLK 48         // REMOTE/MB
#define KTOT 1072       // NBLK + LW
#define NTILES 17       // ceil(1072/64)

typedef __bf16 bf16x8 __attribute__((ext_vector_type(8)));
typedef float  f32x4  __attribute__((ext_vector_type(4)));

__device__ __forceinline__ float bf2f(unsigned short u) {
    unsigned int x = ((unsigned int)u) << 16;
    return __builtin_bit_cast(float, x);
}
__device__ __forceinline__ unsigned short f2bf(float f) {
    unsigned int x = __builtin_bit_cast(unsigned int, f);
    x = x + 0x7fffu + ((x >> 16) & 1u);   // round-to-nearest-even
    return (unsigned short)(x >> 16);
}

// async global->LDS, 16B per lane; LDS dest = wave-uniform base + lane*16
__device__ __forceinline__ void gload16(const unsigned short* gsrc,
                                        unsigned short* ldst) {
    __builtin_amdgcn_global_load_lds(
        (const __attribute__((address_space(1))) void*)gsrc,
        (__attribute__((address_space(3))) void*)ldst,
        16, 0, 0);
}

// ---------- fp32 -> bf16 bulk convert ----------
__global__ void cvt_f32_to_bf16(const float* __restrict__ src,
                                unsigned short* __restrict__ dst, int n) {
    int i = (blockIdx.x * blockDim.x + threadIdx.x) * 4;
    if (i >= n) return;
    float4 v = *(const float4*)(src + i);
    ushort4 o;
    o.x = f2bf(v.x); o.y = f2bf(v.y); o.z = f2bf(v.z); o.w = f2bf(v.w);
    *(ushort4*)(dst + i) = o;
}

// ---------- transpose + convert: src[R][C] f32 -> dst[C][R] bf16 ----------
__global__ void transpose_cvt(const float* __restrict__ src,
                              unsigned short* __restrict__ dst, int R, int C) {
    __shared__ float tile[32][33];
    int ct = blockIdx.x, rt = blockIdx.y;
    int tx = threadIdx.x, ty = threadIdx.y;
    #pragma unroll
    for (int i = ty; i < 32; i += 8)
        tile[i][tx] = src[(size_t)(rt * 32 + i) * C + ct * 32 + tx];
    __syncthreads();
    #pragma unroll
    for (int i = ty; i < 32; i += 8)
        dst[(size_t)(ct * 32 + i) * R + rt * 32 + tx] = f2bf(tile[tx][i]);
}

// ---------- 256x256 8-phase MFMA GEMM (m201-template port) ----------------
// C[M,N] = A[M,K] * BT[N,K]^T.  BK=64, 2 fixed-parity buffers (even->buf0,
// odd->buf1), 128 KiB LDS.  Per K-tile: 4 quadrant phases {ds-read subtile ;
// stage 1 half-tile ; barrier ; setprio+16 MFMA ; barrier}.  vmcnt(4) ONLY
// at phases 4/8 (ledger: retires exactly the next buffer's 4 halves, keeps
// 2 in flight).  Swizzle: phys_chunk = chunk ^ (row&7), both-sides.
// Staging slots (one half per phase, >= one phase after region's last read):
//  ph1 A.h0(t+1)  ph2 A.h1(t+1)  ph3 B.h0(t+2)  ph4 B.h1(t+2)+vmcnt
//  ph5 A.h0(t+2)  ph6 A.h1(t+2)  ph7 B.h0(t+3)  ph8 B.h1(t+3)+vmcnt
// MODE 0 (proj): fused epilogue — RoPE + KV pooling.  MODE 1: f32 store.
template<int MODE>
__global__ __launch_bounds__(512, 2) void gemm8f(
    const unsigned short* __restrict__ A,
    const unsigned short* __restrict__ BT,
    float* __restrict__ outF,
    unsigned short* __restrict__ qcat,
    unsigned short* __restrict__ kp,    // [bg][key][64]
    unsigned short* __restrict__ vt,    // [bg][d][KTOT]
    int M, int N, int K, int nbx)
{
    extern __shared__ __align__(16) unsigned short lds[];  // 65536 ushorts

    const int tid = threadIdx.x;
    const int lane = tid & 63, w = tid >> 6;   // 8 waves: 2M x 4N
    const int wm = w >> 2, wn = w & 3;
    const int l15 = lane & 15, lg = lane >> 4;

    // bijective XCD swizzle (gridDim.x % 8 == 0)
    const int cpx = gridDim.x >> 3;
    const int swz = (blockIdx.x & 7) * cpx + (blockIdx.x >> 3);
    const int bx = swz % nbx, by = swz / nbx;
    const int row0 = by * 256, col0 = bx * 256;

    const unsigned short* Ag = A  + (size_t)row0 * K;
    const unsigned short* Bg = BT + (size_t)col0 * K;

    // buffers (ushort offsets)
    unsigned short* const A0 = lds;
    unsigned short* const B0 = lds + 16384;
    unsigned short* const A1 = lds + 32768;
    unsigned short* const B1 = lds + 49152;

    // staging geometry: half-tile = 128 rows x 64 cols (8 chunks of 16B/row)
    // thread covers dest chunks {w*64+lane, +512}; row=idx>>3, pos=idx&7,
    // source col chunk = pos ^ (row&7)
    const int srow  = w * 8 + (lane >> 3);
    const int scol8 = ((lane & 7) ^ ((lane >> 3) & 7)) * 8;

    // ds_read swizzled chunk offsets: phys = (ks*4+lg) ^ (l15&7)
    const int l7 = lane & 7;            // == l15 & 7
    const int p0 = ((lg) ^ l7) * 8;     // ks=0
    const int p1 = ((4 + lg) ^ l7) * 8; // ks=1
    const int arow = (wm * 128 + l15) * 64;   // + mf*1024
    const int brow = (wn * 64 + l15) * 64;    // + nf*1024

    const int NT = K >> 6;              // BK=64 tiles (even: 32 or 16)
    const int NI = NT >> 1;
    f32x4 acc[8][4] = {};

    auto stgA = [&](unsigned short* Ab, int half, int tt) {
        unsigned short* hb = Ab + half * 8192;
        const unsigned short* src =
            Ag + (size_t)(half * 128 + srow) * K + tt * 64 + scol8;
        gload16(src, hb + w * 512);
        gload16(src + (size_t)64 * K, hb + 4096 + w * 512);
    };
    auto stgB = [&](unsigned short* Bb, int half, int tt) {
        unsigned short* hb = Bb + half * 8192;
        const unsigned short* src =
            Bg + (size_t)(half * 128 + srow) * K + tt * 64 + scol8;
        gload16(src, hb + w * 512);
        gload16(src + (size_t)64 * K, hb + 4096 + w * 512);
    };

    #define LDF(base, off) __builtin_bit_cast(bf16x8, *(const uint4*)&(base)[off])

    // ---- prologue: tile0 all 4 halves -> buf0 ; tile1 B halves -> buf1 ----
    stgB(B0, 0, 0); stgB(B0, 1, 0);
    stgA(A0, 0, 0); stgA(A0, 1, 0);
    stgB(B1, 0, 1); stgB(B1, 1, 1);
    asm volatile("s_waitcnt vmcnt(4)" ::: "memory");   // tile0 landed
    __builtin_amdgcn_s_barrier();

    for (int i = 0; i < NI; ++i) {
        const int t0 = 2 * i;
        const bool st2 = (t0 + 2) < NT;
        bf16x8 af[4][2], b01[2][2], b23[2][2];

        // ======== tile t0 (buf0) ========
        // ph1: rd A[mf0-3]+B[nf0-1] ; stage A.h0(t0+1)->buf1
        #pragma unroll
        for (int mf = 0; mf < 4; mf++) {
            af[mf][0] = LDF(A0, arow + mf * 1024 + p0);
            af[mf][1] = LDF(A0, arow + mf * 1024 + p1);
        }
        #pragma unroll
        for (int nf = 0; nf < 2; nf++) {
            b01[nf][0] = LDF(B0, brow + nf * 1024 + p0);
            b01[nf][1] = LDF(B0, brow + nf * 1024 + p1);
        }
        stgA(A1, 0, t0 + 1);
        __builtin_amdgcn_s_barrier();
        __builtin_amdgcn_s_setprio(1);
        #pragma unroll
        for (int mf = 0; mf < 4; mf++)
            #pragma unroll
            for (int nf = 0; nf < 2; nf++)
                #pragma unroll
                for (int ks = 0; ks < 2; ks++)
                    acc[mf][nf] = __builtin_amdgcn_mfma_f32_16x16x32_bf16(
                        af[mf][ks], b01[nf][ks], acc[mf][nf], 0, 0, 0);
        __builtin_amdgcn_s_setprio(0);
        __builtin_amdgcn_s_barrier();

        // ph2: rd B[nf2-3] ; stage A.h1(t0+1)->buf1
        #pragma unroll
        for (int nf = 0; nf < 2; nf++) {
            b23[nf][0] = LDF(B0, brow + (nf + 2) * 1024 + p0);
            b23[nf][1] = LDF(B0, brow + (nf + 2) * 1024 + p1);
        }
        stgA(A1, 1, t0 + 1);
        __builtin_amdgcn_s_barrier();
        __builtin_amdgcn_s_setprio(1);
        #pragma unroll
        for (int mf = 0; mf < 4; mf++)
            #pragma unroll
            for (int nf = 0; nf < 2; nf++)
                #pragma unroll
                for (int ks = 0; ks < 2; ks++)
                    acc[mf][nf + 2] = __builtin_amdgcn_mfma_f32_16x16x32_bf16(
                        af[mf][ks], b23[nf][ks], acc[mf][nf + 2], 0, 0, 0);
        __builtin_amdgcn_s_setprio(0);
        __builtin_amdgcn_s_barrier();

        // ph3: rd A[mf4-7] ; stage B.h0(t0+2)->buf0
        #pragma unroll
        for (int mf = 0; mf < 4; mf++) {
            af[mf][0] = LDF(A0, arow + (mf + 4) * 1024 + p0);
            af[mf][1] = LDF(A0, arow + (mf + 4) * 1024 + p1);
        }
        if (st2) stgB(B0, 0, t0 + 2);
        __builtin_amdgcn_s_barrier();
        __builtin_amdgcn_s_setprio(1);
        #pragma unroll
        for (int mf = 0; mf < 4; mf++)
            #pragma unroll
            for (int nf = 0; nf < 2; nf++)
                #pragma unroll
                for (int ks = 0; ks < 2; ks++)
                    acc[mf + 4][nf] = __builtin_amdgcn_mfma_f32_16x16x32_bf16(
                        af[mf][ks], b01[nf][ks], acc[mf + 4][nf], 0, 0, 0);
        __builtin_amdgcn_s_setprio(0);
        __builtin_amdgcn_s_barrier();

        // ph4: stage B.h1(t0+2)->buf0 ; boundary vmcnt
        if (st2) stgB(B0, 1, t0 + 2);
        __builtin_amdgcn_s_barrier();
        __builtin_amdgcn_s_setprio(1);
        #pragma unroll
        for (int mf = 0; mf < 4; mf++)
            #pragma unroll
            for (int nf = 0; nf < 2; nf++)
                #pragma unroll
                for (int ks = 0; ks < 2; ks++)
                    acc[mf + 4][nf + 2] = __builtin_amdgcn_mfma_f32_16x16x32_bf16(
                        af[mf][ks], b23[nf][ks], acc[mf + 4][nf + 2], 0, 0, 0);
        __builtin_amdgcn_s_setprio(0);
        if (st2) asm volatile("s_waitcnt vmcnt(4)" ::: "memory");  // t0+1 landed
        else     asm volatile("s_waitcnt vmcnt(0)" ::: "memory");
        __builtin_amdgcn_s_barrier();

        // ======== tile t0+1 (buf1) ========
        // ph5: rd A[mf0-3]+B[nf0-1] (buf1) ; stage A.h0(t0+2)->buf0
        #pragma unroll
        for (int mf = 0; mf < 4; mf++) {
            af[mf][0] = LDF(A1, arow + mf * 1024 + p0);
            af[mf][1] = LDF(A1, arow + mf * 1024 + p1);
        }
        #pragma unroll
        for (int nf = 0; nf < 2; nf++) {
            b01[nf][0] = LDF(B1, brow + nf * 1024 + p0);
            b01[nf][1] = LDF(B1, brow + nf * 1024 + p1);
        }
        if (st2) stgA(A0, 0, t0 + 2);
        __builtin_amdgcn_s_barrier();
        __builtin_amdgcn_s_setprio(1);
        #pragma unroll
        for (int mf = 0; mf < 4; mf++)
            #pragma unroll
            for (int nf = 0; nf < 2; nf++)
                #pragma unroll
                for (int ks = 0; ks < 2; ks++)
                    acc[mf][nf] = __builtin_amdgcn_mfma_f32_16x16x32_bf16(
                        af[mf][ks], b01[nf][ks], acc[mf][nf], 0, 0, 0);
        __builtin_amdgcn_s_setprio(0);
        __builtin_amdgcn_s_barrier();

        // ph6: rd B[nf2-3] (buf1) ; stage A.h1(t0+2)->buf0
        #pragma unroll
        for (int nf = 0; nf < 2; nf++) {
            b23[nf][0] = LDF(B1, brow + (nf + 2) * 1024 + p0);
            b23[nf][1] = LDF(B1, brow + (nf + 2) * 1024 + p1);
        }
        if (st2) stgA(A0, 1, t0 + 2);
        __builtin_amdgcn_s_barrier();
        __builtin_amdgcn_s_setprio(1);
        #pragma unroll
        for (int mf = 0; mf < 4; mf++)
            #pragma unroll
            for (int nf = 0; nf < 2; nf++)
                #pragma unroll
                for (int ks = 0; ks < 2; ks++)
                    acc[mf][nf + 2] = __builtin_amdgcn_mfma_f32_16x16x32_bf16(
                        af[mf][ks], b23[nf][ks], acc[mf][nf + 2], 0, 0, 0);
        __builtin_amdgcn_s_setprio(0);
        __builtin_amdgcn_s_barrier();

        // ph7: rd A[mf4-7] (buf1) ; stage B.h0(t0+3)->buf1
        #pragma unroll
        for (int mf = 0; mf < 4; mf++) {
            af[mf][0] = LDF(A1, arow + (mf + 4) * 1024 + p0);
            af[mf][1] = LDF(A1, arow + (mf + 4) * 1024 + p1);
        }
        if (st2) stgB(B1, 0, t0 + 3);
        __builtin_amdgcn_s_barrier();
        __builtin_amdgcn_s_setprio(1);
        #pragma unroll
        for (int mf = 0; mf < 4; mf++)
            #pragma unroll
            for (int nf = 0; nf < 2; nf++)
                #pragma unroll
                for (int ks = 0; ks < 2; ks++)
                    acc[mf + 4][nf] = __builtin_amdgcn_mfma_f32_16x16x32_bf16(
                        af[mf][ks], b01[nf][ks], acc[mf + 4][nf], 0, 0, 0);
        __builtin_amdgcn_s_setprio(0);
        __builtin_amdgcn_s_barrier();

        // ph8: stage B.h1(t0+3)->buf1 ; boundary vmcnt
        if (st2) stgB(B1, 1, t0 + 3);
        __builtin_amdgcn_s_barrier();
        __builtin_amdgcn_s_setprio(1);
        #pragma unroll
        for (int mf = 0; mf < 4; mf++)
            #pragma unroll
            for (int nf = 0; nf < 2; nf++)
                #pragma unroll
                for (int ks = 0; ks < 2; ks++)
                    acc[mf + 4][nf + 2] = __builtin_amdgcn_mfma_f32_16x16x32_bf16(
                        af[mf][ks], b23[nf][ks], acc[mf + 4][nf + 2], 0, 0, 0);
        __builtin_amdgcn_s_setprio(0);
        if (st2) asm volatile("s_waitcnt vmcnt(4)" ::: "memory");  // t0+2 landed
        else     asm volatile("s_waitcnt vmcnt(0)" ::: "memory");
        __builtin_amdgcn_s_barrier();
    }
    #undef LDF

    // ---- epilogue (validated in R9) ----
    const int rbase = wm * 128;
    if (MODE == 1) {
        #pragma unroll
        for (int mf = 0; mf < 8; mf++)
            #pragma unroll
            for (int nf = 0; nf < 4; nf++)
                #pragma unroll
                for (int r = 0; r < 4; r++) {
                    int row = row0 + rbase + mf * 16 + lg * 4 + r;
                    int col = col0 + wn * 64 + nf * 16 + l15;
                    outF[(size_t)row * N + col] = acc[mf][nf][r];
                }
    } else {
        const int cspan = col0 + wn * 64;
        const int tbase = row0 & 4095;
        const int bq = row0 >> 12;

        if ((cspan >= 512 && cspan < 1024) || (cspan >= 1152 && cspan < 1280)) {
            const float invf = exp2f(-(float)l15 * 0.8304820237218406f);
            #pragma unroll
            for (int mf = 0; mf < 8; mf++) {
                #pragma unroll
                for (int r = 0; r < 4; r++) {
                    float s, c;
                    sincosf((float)(tbase + rbase + mf*16 + lg*4 + r) * invf, &s, &c);
                    float a0 = acc[mf][0][r], a1 = acc[mf][1][r];
                    acc[mf][0][r] = a0 * c - a1 * s;
                    acc[mf][1][r] = a1 * c + a0 * s;
                    float a2 = acc[mf][2][r], a3 = acc[mf][3][r];
                    acc[mf][2][r] = a2 * c - a3 * s;
                    acc[mf][3][r] = a3 * c + a2 * s;
                }
            }
        }

        if (cspan < 1024) {
            #pragma unroll
            for (int nf = 0; nf < 4; nf++) {
                int col = cspan + nf * 16 + l15;
                int h = (col < 512) ? (col >> 5) : ((col - 512) >> 5);
                int d = (col < 512) ? (col & 31) : (32 + (col & 31));
                unsigned short* qb =
                    qcat + (((size_t)(bq * 16 + h)) * 4096 + tbase) * 64 + d;
                #pragma unroll
                for (int mf = 0; mf < 8; mf++)
                    #pragma unroll
                    for (int r = 0; r < 4; r++)
                        qb[(size_t)(rbase + mf*16 + lg*4 + r) * 64] =
                            f2bf(acc[mf][nf][r]);
            }
        } else if (tbase >= REMOTE) {
            #pragma unroll
            for (int nf = 0; nf < 4; nf++) {
                int col = cspan + nf * 16 + l15;
                #pragma unroll
                for (int mf = 0; mf < 8; mf++)
                    #pragma unroll
                    for (int r = 0; r < 4; r++) {
                        int key = tbase + rbase + mf*16 + lg*4 + r - 3024;
                        unsigned short hv = f2bf(acc[mf][nf][r]);
                        if (col < 1280) {
                            int g, dk;
                            if (col < 1152) { g = (col - 1024) >> 5; dk = col & 31; }
                            else            { g = (col - 1152) >> 5; dk = 32 + (col & 31); }
                            kp[(((size_t)(bq*4 + g)) * KTOT + key) * 64 + dk] = hv;
                        } else {
                            int g = (col - 1280) >> 6, dv = col & 63;
                            vt[(((size_t)(bq*4 + g)) * 64 + dv) * KTOT + key] = hv;
                        }
                    }
            }
        } else {
            #pragma unroll
            for (int half = 0; half < 2; half++) {
                #pragma unroll
                for (int nf = 0; nf < 4; nf++) {
                    float ps = 0.f;
                    #pragma unroll
                    for (int mf = half * 4; mf < half * 4 + 4; mf++)
                        #pragma unroll
                        for (int r = 0; r < 4; r++) ps += acc[mf][nf][r];
                    ps += __shfl_xor(ps, 16);
                    ps += __shfl_xor(ps, 32);
                    if (lane < 16) {
                        int col = cspan + nf * 16 + l15;
                        int key = ((tbase + rbase) >> 6) + half;
                        unsigned short hv = f2bf(ps * (1.f / 64.f));
                        if (col < 1280) {
                            int g, dk;
                            if (col < 1152) { g = (col - 1024) >> 5; dk = col & 31; }
                            else            { g = (col - 1152) >> 5; dk = 32 + (col & 31); }
                            kp[(((size_t)(bq*4 + g)) * KTOT + key) * 64 + dk] = hv;
                        } else {
                            int g = (col - 1280) >> 6, dv = col & 63;
                            vt[(((size_t)(bq*4 + g)) * 64 + dv) * KTOT + key] = hv;
                        }
                    }
                }
            }
        }
    }
}

// ---------- MFMA flash attention, wave-independent (NO barriers) ----------
__global__ __launch_bounds__(256) void attn_fwd(
    const unsigned short* __restrict__ qcat,
    const unsigned short* __restrict__ kp,   // [bg][key][64]
    const unsigned short* __restrict__ vt,   // [bg][d][KTOT]
    const float* __restrict__ ls,
    unsigned short* __restrict__ attn_out)
{
    __shared__ unsigned short Pl[4][32][72];   // per-wave P tile (bf16)

    const int tid = threadIdx.x;
    const int lane = tid & 63, w = tid >> 6;
    const int l15 = lane & 15, lg = lane >> 4;

    const int wid = blockIdx.x * 4 + w;        // 0..4095
    const int hb = wid & 31;
    const int iu = wid >> 5;                   // schedule slot 0..127
    int i;
    if (iu < 32)       i = 127 - iu;
    else if (iu == 32) i = 0;
    else if (iu == 33) i = 1;
    else               i = iu - 32;
    const int h = hb & 15, b = hb >> 4, g = h >> 2;
    const int q0 = i * 32;

    int ktmax;
    if (q0 < 64) ktmax = NTILES;               // uniform rows: all keys
    else {
        int lastkey = q0 + 31 - 3024;          // max valid local key index
        ktmax = (lastkey < NBLK) ? 1 : (lastkey / 64 + 1);
    }

    const float sc = __expf(ls[h]) * 0.17677669529663687f;   // exp(ls)/sqrt(32)

    bf16x8 aq[2][2];
    const unsigned short* qbase = qcat + (((size_t)(b * 16 + h)) * T_ + q0) * 64;
    #pragma unroll
    for (int rf = 0; rf < 2; rf++)
        #pragma unroll
        for (int kh = 0; kh < 2; kh++)
            aq[rf][kh] = __builtin_bit_cast(bf16x8,
                *(const uint4*)(qbase + (size_t)(rf*16 + l15)*64 + kh*32 + lg*8));

    float m[2][4], lrun[2][4];
    #pragma unroll
    for (int rf = 0; rf < 2; rf++)
        #pragma unroll
        for (int r = 0; r < 4; r++) { m[rf][r] = -1e9f; lrun[rf][r] = 0.f; }
    f32x4 oacc[2][4] = {};

    const unsigned short* kbase = kp + ((size_t)(b * 4 + g)) * KTOT * 64;
    const unsigned short* vbase = vt + ((size_t)(b * 4 + g)) * 64 * KTOT;

    for (int kt = 0; kt < ktmax; kt++) {
        const int kb = kt * 64;

        bf16x8 bk[4][2];
        #pragma unroll
        for (int nf = 0; nf < 4; nf++) {
            int krow = kb + nf*16 + l15;
            int krc = krow < KTOT ? krow : KTOT - 1;     // clamp (masked later)
            #pragma unroll
            for (int kh = 0; kh < 2; kh++)
                bk[nf][kh] = __builtin_bit_cast(bf16x8,
                    *(const uint4*)(kbase + (size_t)krc * 64 + kh*32 + lg*8));
        }

        f32x4 s[2][4] = {};
        #pragma unroll
        for (int rf = 0; rf < 2; rf++)
            #pragma unroll
            for (int nf = 0; nf < 4; nf++)
                #pragma unroll
                for (int kh = 0; kh < 2; kh++)
                    s[rf][nf] = __builtin_amdgcn_mfma_f32_16x16x32_bf16(
                                    aq[rf][kh], bk[nf][kh], s[rf][nf], 0, 0, 0);

        bf16x8 bv[4][2];
        #pragma unroll
        for (int nfv = 0; nfv < 4; nfv++)
            #pragma unroll
            for (int kh = 0; kh < 2; kh++) {
                int kc = kb + kh*32 + lg*8;
                int kcc = (kc + 8 <= KTOT) ? kc : KTOT - 8;  // clamp (P=0 there)
                bv[nfv][kh] = __builtin_bit_cast(bf16x8,
                    *(const uint4*)(vbase + (size_t)(nfv*16 + l15) * KTOT + kcc));
            }

        #pragma unroll
        for (int rf = 0; rf < 2; rf++) {
            #pragma unroll
            for (int r = 0; r < 4; r++) {
                const int qpos = q0 + rf*16 + lg*4 + r;
                float vals[4];
                float tmax = -INFINITY;
                #pragma unroll
                for (int nf = 0; nf < 4; nf++) {
                    int key = kb + nf*16 + l15;
                    float v = s[rf][nf][r] * sc;
                    int kpos = (key < NBLK) ? key * 64 + 63 : 3024 + key;
                    v = (key < KTOT) ? ((kpos <= qpos) ? v : -1e9f) : -INFINITY;
                    vals[nf] = v;
                    tmax = fmaxf(tmax, v);
                }
                #pragma unroll
                for (int d = 1; d < 16; d <<= 1)
                    tmax = fmaxf(tmax, __shfl_xor(tmax, d));
                float mn = fmaxf(m[rf][r], tmax);
                float scl = __expf(m[rf][r] - mn);
                m[rf][r] = mn;
                float rs = 0.f;
                #pragma unroll
                for (int nf = 0; nf < 4; nf++) {
                    unsigned short pb = f2bf(__expf(vals[nf] - mn));
                    rs += bf2f(pb);          // sum the ROUNDED p: exact convex comb
                    Pl[w][rf*16 + lg*4 + r][nf*16 + l15] = pb;
                }
                #pragma unroll
                for (int d = 1; d < 16; d <<= 1)
                    rs += __shfl_xor(rs, d);
                lrun[rf][r] = lrun[rf][r] * scl + rs;
                #pragma unroll
                for (int nfv = 0; nfv < 4; nfv++)
                    oacc[rf][nfv][r] *= scl;
            }
        }

        #pragma unroll
        for (int rf = 0; rf < 2; rf++) {
            bf16x8 pa[2];
            #pragma unroll
            for (int kh = 0; kh < 2; kh++)
                pa[kh] = __builtin_bit_cast(bf16x8,
                    *(const uint4*)&Pl[w][rf*16 + l15][kh*32 + lg*8]);
            #pragma unroll
            for (int nfv = 0; nfv < 4; nfv++)
                #pragma unroll
                for (int kh = 0; kh < 2; kh++)
                    oacc[rf][nfv] = __builtin_amdgcn_mfma_f32_16x16x32_bf16(
                                        pa[kh], bv[nfv][kh], oacc[rf][nfv], 0, 0, 0);
        }
    }

    #pragma unroll
    for (int rf = 0; rf < 2; rf++) {
        #pragma unroll
        for (int r = 0; r < 4; r++) {
            float inv = 1.f / lrun[rf][r];
            int q = q0 + rf*16 + lg*4 + r;
            size_t obase = ((size_t)(b * T_ + q)) * 1024 + h * 64;
            #pragma unroll
            for (int nfv = 0; nfv < 4; nfv++)
                attn_out[obase + nfv*16 + l15] = f2bf(oacc[rf][nfv][r] * inv);
        }
    }
}

// ---------- host launch ----------
extern "C" void kernel_launch(void* const* d_in, const int* in_sizes, int n_in,
                              void* d_out, int out_size, void* d_ws, size_t ws_size,
                              hipStream_t stream) {
    const float* x      = (const float*)d_in[0];
    const float* Wq_sem = (const float*)d_in[1];
    const float* Wk_sem = (const float*)d_in[2];
    const float* Wq_geo = (const float*)d_in[3];
    const float* Wk_geo = (const float*)d_in[4];
    const float* Wv     = (const float*)d_in[5];
    const float* Wo     = (const float*)d_in[6];
    const float* ls     = (const float*)d_in[7];

    char* w = (char*)d_ws;
    auto alloc = [&](size_t bytes) {
        char* p = w;
        w += (bytes + 255) & ~(size_t)255;
        return p;
    };
    unsigned short* xb    = (unsigned short*)alloc((size_t)8192 * 2048 * 2);
    unsigned short* WcatT = (unsigned short*)alloc((size_t)1536 * 2048 * 2);
    unsigned short* WoT   = (unsigned short*)alloc((size_t)2048 * 1024 * 2);
    unsigned short* qcat  = (unsigned short*)alloc((size_t)2 * 16 * 4096 * 64 * 2);
    unsigned short* kp    = (unsigned short*)alloc((size_t)2 * 4 * 1072 * 64 * 2);
    unsigned short* vt    = (unsigned short*)alloc((size_t)2 * 4 * 1072 * 64 * 2);
    unsigned short* aout  = (unsigned short*)alloc((size_t)8192 * 1024 * 2);

    // allow 128 KiB dynamic LDS (idempotent)
    hipFuncSetAttribute(reinterpret_cast<const void*>(&gemm8f<0>),
                        hipFuncAttributeMaxDynamicSharedMemorySize, 131072);
    hipFuncSetAttribute(reinterpret_cast<const void*>(&gemm8f<1>),
                        hipFuncAttributeMaxDynamicSharedMemorySize, 131072);

    // 1) x -> bf16
    cvt_f32_to_bf16<<<16384, 256, 0, stream>>>(x, xb, 8192 * 2048);

    // 2) weights -> bf16, transposed to [N][K]
    dim3 tb(32, 8);
    transpose_cvt<<<dim3(16, 64), tb, 0, stream>>>(Wq_sem, WcatT + (size_t)0    * 2048, 2048, 512);
    transpose_cvt<<<dim3(16, 64), tb, 0, stream>>>(Wq_geo, WcatT + (size_t)512  * 2048, 2048, 512);
    transpose_cvt<<<dim3( 4, 64), tb, 0, stream>>>(Wk_sem, WcatT + (size_t)1024 * 2048, 2048, 128);
    transpose_cvt<<<dim3( 4, 64), tb, 0, stream>>>(Wk_geo, WcatT + (size_t)1152 * 2048, 2048, 128);
    transpose_cvt<<<dim3( 8, 64), tb, 0, stream>>>(Wv,     WcatT + (size_t)1280 * 2048, 2048, 256);
    transpose_cvt<<<dim3(64, 32), tb, 0, stream>>>(Wo, WoT, 1024, 2048);

    // 3) fused projection GEMM (+RoPE +pooling) -> qcat / kp / vt
    gemm8f<0><<<192, 512, 131072, stream>>>(
        xb, WcatT, nullptr, qcat, kp, vt, 8192, 1536, 2048, 6);

    // 4) wave-independent MFMA flash attention
    attn_fwd<<<dim3(1024), 256, 0, stream>>>(qcat, kp, vt, ls, aout);

    // 5) output projection -> d_out (fp32)
    gemm8f<1><<<256, 512, 131072, stream>>>(
        aout, WoT, (float*)d_out, nullptr, nullptr, nullptr, 8192, 2048, 1024, 8);
}

// Round 11
// 193.473 us; speedup vs baseline: 1.1099x; 1.1099x over previous
//
#include <hip/hip_runtime.h>
#include <math.h>

// ---------- constants ----------
#define B_  2
#define T_  4096
#define DM  2048
#define H_  16
#define HKV 4
#define DV_ 64
#define MB_ 64
#define LW_ 1024
#define REMOTE 3072     // T - LW
#define NBLK 48         // REMOTE/MB
#define KTOT 1072       // NBLK + LW
#define NTILES 17       // ceil(1072/64)

typedef __bf16 bf16x8 __attribute__((ext_vector_type(8)));
typedef float  f32x4  __attribute__((ext_vector_type(4)));

__device__ __forceinline__ float bf2f(unsigned short u) {
    unsigned int x = ((unsigned int)u) << 16;
    return __builtin_bit_cast(float, x);
}
__device__ __forceinline__ unsigned short f2bf(float f) {
    unsigned int x = __builtin_bit_cast(unsigned int, f);
    x = x + 0x7fffu + ((x >> 16) & 1u);   // round-to-nearest-even
    return (unsigned short)(x >> 16);
}

// async global->LDS, 16B per lane; LDS dest = wave-uniform base + lane*16
__device__ __forceinline__ void gload16(const unsigned short* gsrc,
                                        unsigned short* ldst) {
    __builtin_amdgcn_global_load_lds(
        (const __attribute__((address_space(1))) void*)gsrc,
        (__attribute__((address_space(3))) void*)ldst,
        16, 0, 0);
}

// ---------- fp32 -> bf16 bulk convert (grid-stride) ----------
__global__ void cvt_f32_to_bf16(const float* __restrict__ src,
                                unsigned short* __restrict__ dst, int n4) {
    int stride = gridDim.x * blockDim.x;
    for (int i = blockIdx.x * blockDim.x + threadIdx.x; i < n4; i += stride) {
        float4 v = ((const float4*)src)[i];
        ushort4 o = make_ushort4(f2bf(v.x), f2bf(v.y), f2bf(v.z), f2bf(v.w));
        ((ushort4*)dst)[i] = o;
    }
}

// ---------- ALL weight transposes in one launch ----------
// segments: [0,1024) Wq_sem  [1024,2048) Wq_geo  [2048,2304) Wk_sem
// [2304,2560) Wk_geo  [2560,3072) Wv  [3072,5120) Wo
__global__ void transpose_all(const float* __restrict__ Wq_sem,
                              const float* __restrict__ Wq_geo,
                              const float* __restrict__ Wk_sem,
                              const float* __restrict__ Wk_geo,
                              const float* __restrict__ Wv,
                              const float* __restrict__ Wo,
                              unsigned short* __restrict__ WcatT,
                              unsigned short* __restrict__ WoT) {
    __shared__ float tile[32][33];
    const int bid = blockIdx.x;
    const float* src; unsigned short* dst; int R, C, tiles_x, lt;
    if (bid < 1024)      { src = Wq_sem; dst = WcatT;                       R = 2048; C = 512;  tiles_x = 16; lt = bid; }
    else if (bid < 2048) { src = Wq_geo; dst = WcatT + (size_t)512  * 2048; R = 2048; C = 512;  tiles_x = 16; lt = bid - 1024; }
    else if (bid < 2304) { src = Wk_sem; dst = WcatT + (size_t)1024 * 2048; R = 2048; C = 128;  tiles_x = 4;  lt = bid - 2048; }
    else if (bid < 2560) { src = Wk_geo; dst = WcatT + (size_t)1152 * 2048; R = 2048; C = 128;  tiles_x = 4;  lt = bid - 2304; }
    else if (bid < 3072) { src = Wv;     dst = WcatT + (size_t)1280 * 2048; R = 2048; C = 256;  tiles_x = 8;  lt = bid - 2560; }
    else                 { src = Wo;     dst = WoT;                         R = 1024; C = 2048; tiles_x = 64; lt = bid - 3072; }
    const int ct = lt % tiles_x, rt = lt / tiles_x;
    const int tx = threadIdx.x, ty = threadIdx.y;
    #pragma unroll
    for (int i = ty; i < 32; i += 8)
        tile[i][tx] = src[(size_t)(rt * 32 + i) * C + ct * 32 + tx];
    __syncthreads();
    #pragma unroll
    for (int i = ty; i < 32; i += 8)
        dst[(size_t)(ct * 32 + i) * R + rt * 32 + tx] = f2bf(tile[tx][i]);
}

// ---------- 128x128 4-wave MFMA GEMM ----------
// C[M,N] = A[M,K] * BT[N,K]^T.  BK=32.  LDS swizzle both-sides (verified
// conflict-free).  MODE 0 (proj): ring-3 (48KB) + counted vmcnt(4), 3
// blocks/CU (grid 768 = exact single round); fused RoPE+pool epilogue.
// MODE 1 (Wo): ring-2 dbuf (32KB) + vmcnt(0)/tile, 4 blocks/CU so the
// 1024-block grid packs in ONE round (R8's 3/CU ran 1.33 rounds).
template<int MODE>
__global__ __launch_bounds__(256, MODE == 1 ? 4 : 3) void gemmP(
    const unsigned short* __restrict__ A,
    const unsigned short* __restrict__ BT,
    float* __restrict__ outF,
    unsigned short* __restrict__ qcat,
    unsigned short* __restrict__ kp,    // [bg][key][64]
    unsigned short* __restrict__ vt,    // [bg][d][KTOT]
    int M, int N, int K, int nbx)
{
    constexpr int RING = (MODE == 1) ? 2 : 3;
    extern __shared__ __align__(16) unsigned short lds[];  // RING*(4096A+4096B)

    const int tid = threadIdx.x;
    const int lane = tid & 63, w = tid >> 6;   // 4 waves: 2x2
    const int wr = w >> 1, wc = w & 1;
    const int l15 = lane & 15, lg = lane >> 4;

    // bijective XCD swizzle (gridDim.x % 8 == 0)
    const int cpx = gridDim.x >> 3;
    const int swz = (blockIdx.x & 7) * cpx + (blockIdx.x >> 3);
    const int bx = swz % nbx, by = swz / nbx;
    const int row0 = by * 128, col0 = bx * 128;

    const int scol = ((lane & 3) ^ ((lane >> 3) & 3)) * 8;
    const int srA = w * 16 + (lane >> 2);           // + j*64
    const unsigned short* Ag = A  + (size_t)row0 * K;
    const unsigned short* Bg = BT + (size_t)col0 * K;

    const int rdsw = (lg ^ ((l15 >> 1) & 3)) * 8;
    const int aoff = (wr * 64 + l15) * 32 + rdsw;   // + mf*512
    const int boff = (wc * 64 + l15) * 32 + rdsw;   // + nf*512

    const int NT = K >> 5;
    f32x4 acc[4][4] = {};

    auto stage = [&](int s, int kk) {
        unsigned short* sa = lds + s * 8192;
        unsigned short* sb = sa + 4096;
        #pragma unroll
        for (int j = 0; j < 2; j++) {
            gload16(Ag + (size_t)(srA + j * 64) * K + kk + scol,
                    sa + (j * 256 + w * 64) * 8);
            gload16(Bg + (size_t)(srA + j * 64) * K + kk + scol,
                    sb + (j * 256 + w * 64) * 8);
        }
    };

    // prologue
    if (RING == 3) {
        stage(0, 0);
        stage(1, 32);
        asm volatile("s_waitcnt vmcnt(4)" ::: "memory");
    } else {
        stage(0, 0);
        asm volatile("s_waitcnt vmcnt(0)" ::: "memory");
    }

    int rs = 0;
    for (int t = 0; t < NT; ++t) {
        __builtin_amdgcn_s_barrier();            // write-slot readers done
        if (RING == 3) {
            if (t + 2 < NT) stage(rs == 0 ? 2 : rs - 1, (t + 2) << 5);
        } else {
            if (t + 1 < NT) stage(rs ^ 1, (t + 1) << 5);
        }

        const unsigned short* As_ = lds + rs * 8192;
        const unsigned short* Bs_ = As_ + 4096;
        bf16x8 af[4], bfr[4];
        #pragma unroll
        for (int mf = 0; mf < 4; mf++)
            af[mf] = __builtin_bit_cast(bf16x8, *(const uint4*)&As_[aoff + mf * 512]);
        #pragma unroll
        for (int nf = 0; nf < 4; nf++)
            bfr[nf] = __builtin_bit_cast(bf16x8, *(const uint4*)&Bs_[boff + nf * 512]);

        __builtin_amdgcn_s_setprio(1);
        #pragma unroll
        for (int mf = 0; mf < 4; mf++)
            #pragma unroll
            for (int nf = 0; nf < 4; nf++)
                acc[mf][nf] = __builtin_amdgcn_mfma_f32_16x16x32_bf16(
                                  af[mf], bfr[nf], acc[mf][nf], 0, 0, 0);
        __builtin_amdgcn_s_setprio(0);

        if (RING == 3) {
            if (t + 2 < NT) asm volatile("s_waitcnt vmcnt(4)" ::: "memory");
            else            asm volatile("s_waitcnt vmcnt(0)" ::: "memory");
            rs = (rs == 2) ? 0 : rs + 1;
        } else {
            if (t + 1 < NT) asm volatile("s_waitcnt vmcnt(0)" ::: "memory");
            rs ^= 1;
        }
    }

    // ---- epilogue ----
    if (MODE == 1) {
        #pragma unroll
        for (int mf = 0; mf < 4; mf++)
            #pragma unroll
            for (int nf = 0; nf < 4; nf++)
                #pragma unroll
                for (int r = 0; r < 4; r++) {
                    int row = row0 + wr * 64 + mf * 16 + lg * 4 + r;
                    int col = col0 + wc * 64 + nf * 16 + l15;
                    outF[(size_t)row * N + col] = acc[mf][nf][r];
                }
    } else {
        const int cspan = col0 + wc * 64;       // wave col base (64-aligned)
        const int tbase = row0 & 4095;          // t of tile row 0 (b uniform)
        const int bq = row0 >> 12;

        // RoPE on geo spans: pair (d, d+16) == (nf, nf+1) in-fragment
        if ((cspan >= 512 && cspan < 1024) || (cspan >= 1152 && cspan < 1280)) {
            const float invf = exp2f(-(float)l15 * 0.8304820237218406f);
            #pragma unroll
            for (int mf = 0; mf < 4; mf++) {
                #pragma unroll
                for (int r = 0; r < 4; r++) {
                    float s, c;
                    sincosf((float)(tbase + wr*64 + mf*16 + lg*4 + r) * invf, &s, &c);
                    float a0 = acc[mf][0][r], a1 = acc[mf][1][r];
                    acc[mf][0][r] = a0 * c - a1 * s;
                    acc[mf][1][r] = a1 * c + a0 * s;
                    float a2 = acc[mf][2][r], a3 = acc[mf][3][r];
                    acc[mf][2][r] = a2 * c - a3 * s;
                    acc[mf][3][r] = a3 * c + a2 * s;
                }
            }
        }

        if (cspan < 1024) {
            // ---- Q -> qcat [b][h][t][64] ----
            #pragma unroll
            for (int nf = 0; nf < 4; nf++) {
                int col = cspan + nf * 16 + l15;
                int h = (col < 512) ? (col >> 5) : ((col - 512) >> 5);
                int d = (col < 512) ? (col & 31) : (32 + (col & 31));
                unsigned short* qb =
                    qcat + (((size_t)(bq * 16 + h)) * 4096 + tbase) * 64 + d;
                #pragma unroll
                for (int mf = 0; mf < 4; mf++)
                    #pragma unroll
                    for (int r = 0; r < 4; r++)
                        qb[(size_t)(wr*64 + mf*16 + lg*4 + r) * 64] =
                            f2bf(acc[mf][nf][r]);
            }
        } else if (tbase >= REMOTE) {
            // ---- local K/V rows -> full-res keys 48..1071 ----
            #pragma unroll
            for (int nf = 0; nf < 4; nf++) {
                int col = cspan + nf * 16 + l15;
                #pragma unroll
                for (int mf = 0; mf < 4; mf++)
                    #pragma unroll
                    for (int r = 0; r < 4; r++) {
                        int key = tbase + wr*64 + mf*16 + lg*4 + r - 3024;
                        unsigned short hv = f2bf(acc[mf][nf][r]);
                        if (col < 1280) {
                            int g, dk;
                            if (col < 1152) { g = (col - 1024) >> 5; dk = col & 31; }
                            else            { g = (col - 1152) >> 5; dk = 32 + (col & 31); }
                            kp[(((size_t)(bq*4 + g)) * KTOT + key) * 64 + dk] = hv;
                        } else {
                            int g = (col - 1280) >> 6, dv = col & 63;
                            vt[(((size_t)(bq*4 + g)) * 64 + dv) * KTOT + key] = hv;
                        }
                    }
            }
        } else {
            // ---- remote K/V rows -> mem-block pooled (wr half = one block) ----
            #pragma unroll
            for (int nf = 0; nf < 4; nf++) {
                float ps = 0.f;
                #pragma unroll
                for (int mf = 0; mf < 4; mf++)
                    #pragma unroll
                    for (int r = 0; r < 4; r++) ps += acc[mf][nf][r];
                ps += __shfl_xor(ps, 16);
                ps += __shfl_xor(ps, 32);
                if (lane < 16) {
                    int col = cspan + nf * 16 + l15;
                    int key = (tbase >> 6) + wr;
                    unsigned short hv = f2bf(ps * (1.f / 64.f));
                    if (col < 1280) {
                        int g, dk;
                        if (col < 1152) { g = (col - 1024) >> 5; dk = col & 31; }
                        else            { g = (col - 1152) >> 5; dk = 32 + (col & 31); }
                        kp[(((size_t)(bq*4 + g)) * KTOT + key) * 64 + dk] = hv;
                    } else {
                        int g = (col - 1280) >> 6, dv = col & 63;
                        vt[(((size_t)(bq*4 + g)) * 64 + dv) * KTOT + key] = hv;
                    }
                }
            }
        }
    }
}

// ---------- MFMA flash attention, wave-independent (NO barriers) ----------
__global__ __launch_bounds__(256) void attn_fwd(
    const unsigned short* __restrict__ qcat,
    const unsigned short* __restrict__ kp,   // [bg][key][64]
    const unsigned short* __restrict__ vt,   // [bg][d][KTOT]
    const float* __restrict__ ls,
    unsigned short* __restrict__ attn_out)
{
    __shared__ unsigned short Pl[4][32][72];   // per-wave P tile (bf16)

    const int tid = threadIdx.x;
    const int lane = tid & 63, w = tid >> 6;
    const int l15 = lane & 15, lg = lane >> 4;

    const int wid = blockIdx.x * 4 + w;        // 0..4095
    const int hb = wid & 31;
    const int iu = wid >> 5;                   // schedule slot 0..127
    int i;
    if (iu < 32)       i = 127 - iu;
    else if (iu == 32) i = 0;
    else if (iu == 33) i = 1;
    else               i = iu - 32;
    const int h = hb & 15, b = hb >> 4, g = h >> 2;
    const int q0 = i * 32;

    int ktmax;
    if (q0 < 64) ktmax = NTILES;               // uniform rows: all keys
    else {
        int lastkey = q0 + 31 - 3024;          // max valid local key index
        ktmax = (lastkey < NBLK) ? 1 : (lastkey / 64 + 1);
    }

    const float sc = __expf(ls[h]) * 0.17677669529663687f;   // exp(ls)/sqrt(32)

    bf16x8 aq[2][2];
    const unsigned short* qbase = qcat + (((size_t)(b * 16 + h)) * T_ + q0) * 64;
    #pragma unroll
    for (int rf = 0; rf < 2; rf++)
        #pragma unroll
        for (int kh = 0; kh < 2; kh++)
            aq[rf][kh] = __builtin_bit_cast(bf16x8,
                *(const uint4*)(qbase + (size_t)(rf*16 + l15)*64 + kh*32 + lg*8));

    float m[2][4], lrun[2][4];
    #pragma unroll
    for (int rf = 0; rf < 2; rf++)
        #pragma unroll
        for (int r = 0; r < 4; r++) { m[rf][r] = -1e9f; lrun[rf][r] = 0.f; }
    f32x4 oacc[2][4] = {};

    const unsigned short* kbase = kp + ((size_t)(b * 4 + g)) * KTOT * 64;
    const unsigned short* vbase = vt + ((size_t)(b * 4 + g)) * 64 * KTOT;

    for (int kt = 0; kt < ktmax; kt++) {
        const int kb = kt * 64;

        bf16x8 bk[4][2];
        #pragma unroll
        for (int nf = 0; nf < 4; nf++) {
            int krow = kb + nf*16 + l15;
            int krc = krow < KTOT ? krow : KTOT - 1;     // clamp (masked later)
            #pragma unroll
            for (int kh = 0; kh < 2; kh++)
                bk[nf][kh] = __builtin_bit_cast(bf16x8,
                    *(const uint4*)(kbase + (size_t)krc * 64 + kh*32 + lg*8));
        }

        f32x4 s[2][4] = {};
        #pragma unroll
        for (int rf = 0; rf < 2; rf++)
            #pragma unroll
            for (int nf = 0; nf < 4; nf++)
                #pragma unroll
                for (int kh = 0; kh < 2; kh++)
                    s[rf][nf] = __builtin_amdgcn_mfma_f32_16x16x32_bf16(
                                    aq[rf][kh], bk[nf][kh], s[rf][nf], 0, 0, 0);

        bf16x8 bv[4][2];
        #pragma unroll
        for (int nfv = 0; nfv < 4; nfv++)
            #pragma unroll
            for (int kh = 0; kh < 2; kh++) {
                int kc = kb + kh*32 + lg*8;
                int kcc = (kc + 8 <= KTOT) ? kc : KTOT - 8;  // clamp (P=0 there)
                bv[nfv][kh] = __builtin_bit_cast(bf16x8,
                    *(const uint4*)(vbase + (size_t)(nfv*16 + l15) * KTOT + kcc));
            }

        #pragma unroll
        for (int rf = 0; rf < 2; rf++) {
            #pragma unroll
            for (int r = 0; r < 4; r++) {
                const int qpos = q0 + rf*16 + lg*4 + r;
                float vals[4];
                float tmax = -INFINITY;
                #pragma unroll
                for (int nf = 0; nf < 4; nf++) {
                    int key = kb + nf*16 + l15;
                    float v = s[rf][nf][r] * sc;
                    int kpos = (key < NBLK) ? key * 64 + 63 : 3024 + key;
                    v = (key < KTOT) ? ((kpos <= qpos) ? v : -1e9f) : -INFINITY;
                    vals[nf] = v;
                    tmax = fmaxf(tmax, v);
                }
                #pragma unroll
                for (int d = 1; d < 16; d <<= 1)
                    tmax = fmaxf(tmax, __shfl_xor(tmax, d));
                float mn = fmaxf(m[rf][r], tmax);
                float scl = __expf(m[rf][r] - mn);
                m[rf][r] = mn;
                float rs = 0.f;
                #pragma unroll
                for (int nf = 0; nf < 4; nf++) {
                    unsigned short pb = f2bf(__expf(vals[nf] - mn));
                    rs += bf2f(pb);          // sum the ROUNDED p: exact convex comb
                    Pl[w][rf*16 + lg*4 + r][nf*16 + l15] = pb;
                }
                #pragma unroll
                for (int d = 1; d < 16; d <<= 1)
                    rs += __shfl_xor(rs, d);
                lrun[rf][r] = lrun[rf][r] * scl + rs;
                #pragma unroll
                for (int nfv = 0; nfv < 4; nfv++)
                    oacc[rf][nfv][r] *= scl;
            }
        }

        #pragma unroll
        for (int rf = 0; rf < 2; rf++) {
            bf16x8 pa[2];
            #pragma unroll
            for (int kh = 0; kh < 2; kh++)
                pa[kh] = __builtin_bit_cast(bf16x8,
                    *(const uint4*)&Pl[w][rf*16 + l15][kh*32 + lg*8]);
            #pragma unroll
            for (int nfv = 0; nfv < 4; nfv++)
                #pragma unroll
                for (int kh = 0; kh < 2; kh++)
                    oacc[rf][nfv] = __builtin_amdgcn_mfma_f32_16x16x32_bf16(
                                        pa[kh], bv[nfv][kh], oacc[rf][nfv], 0, 0, 0);
        }
    }

    #pragma unroll
    for (int rf = 0; rf < 2; rf++) {
        #pragma unroll
        for (int r = 0; r < 4; r++) {
            float inv = 1.f / lrun[rf][r];
            int q = q0 + rf*16 + lg*4 + r;
            size_t obase = ((size_t)(b * T_ + q)) * 1024 + h * 64;
            #pragma unroll
            for (int nfv = 0; nfv < 4; nfv++)
                attn_out[obase + nfv*16 + l15] = f2bf(oacc[rf][nfv][r] * inv);
        }
    }
}

// ---------- host launch ----------
extern "C" void kernel_launch(void* const* d_in, const int* in_sizes, int n_in,
                              void* d_out, int out_size, void* d_ws, size_t ws_size,
                              hipStream_t stream) {
    const float* x      = (const float*)d_in[0];
    const float* Wq_sem = (const float*)d_in[1];
    const float* Wk_sem = (const float*)d_in[2];
    const float* Wq_geo = (const float*)d_in[3];
    const float* Wk_geo = (const float*)d_in[4];
    const float* Wv     = (const float*)d_in[5];
    const float* Wo     = (const float*)d_in[6];
    const float* ls     = (const float*)d_in[7];

    char* w = (char*)d_ws;
    auto alloc = [&](size_t bytes) {
        char* p = w;
        w += (bytes + 255) & ~(size_t)255;
        return p;
    };
    unsigned short* xb    = (unsigned short*)alloc((size_t)8192 * 2048 * 2);
    unsigned short* WcatT = (unsigned short*)alloc((size_t)1536 * 2048 * 2);
    unsigned short* WoT   = (unsigned short*)alloc((size_t)2048 * 1024 * 2);
    unsigned short* qcat  = (unsigned short*)alloc((size_t)2 * 16 * 4096 * 64 * 2);
    unsigned short* kp    = (unsigned short*)alloc((size_t)2 * 4 * 1072 * 64 * 2);
    unsigned short* vt    = (unsigned short*)alloc((size_t)2 * 4 * 1072 * 64 * 2);
    unsigned short* aout  = (unsigned short*)alloc((size_t)8192 * 1024 * 2);

    hipFuncSetAttribute(reinterpret_cast<const void*>(&gemmP<0>),
                        hipFuncAttributeMaxDynamicSharedMemorySize, 49152);
    hipFuncSetAttribute(reinterpret_cast<const void*>(&gemmP<1>),
                        hipFuncAttributeMaxDynamicSharedMemorySize, 32768);

    // 1) x -> bf16 (grid-stride)
    cvt_f32_to_bf16<<<2048, 256, 0, stream>>>(x, xb, 8192 * 2048 / 4);

    // 2) all weight transposes in ONE launch
    transpose_all<<<5120, dim3(32, 8), 0, stream>>>(
        Wq_sem, Wq_geo, Wk_sem, Wk_geo, Wv, Wo, WcatT, WoT);

    // 3) fused projection GEMM (+RoPE +pooling) -> qcat / kp / vt
    //    768 blocks = exactly 3/CU, single round
    gemmP<0><<<768, 256, 49152, stream>>>(
        xb, WcatT, nullptr, qcat, kp, vt, 8192, 1536, 2048, 12);

    // 4) wave-independent MFMA flash attention
    attn_fwd<<<dim3(1024), 256, 0, stream>>>(qcat, kp, vt, ls, aout);

    // 5) output projection -> d_out (fp32); 1024 blocks at 4/CU = single round
    gemmP<1><<<1024, 256, 32768, stream>>>(
        aout, WoT, (float*)d_out, nullptr, nullptr, nullptr, 8192, 2048, 1024, 16);
}

// Round 12
// 186.585 us; speedup vs baseline: 1.1509x; 1.0369x over previous
//
#include <hip/hip_runtime.h>
#include <math.h>

// ---------- constants ----------
#define B_  2
#define T_  4096
#define DM  2048
#define H_  16
#define HKV 4
#define DV_ 64
#define MB_ 64
#define LW_ 1024
#define REMOTE 3072     // T - LW
#define NBLK 48         // REMOTE/MB
#define KTOT 1072       // NBLK + LW
#define NTILES 17       // ceil(1072/64)

typedef __bf16 bf16x8 __attribute__((ext_vector_type(8)));
typedef float  f32x4  __attribute__((ext_vector_type(4)));

__device__ __forceinline__ float bf2f(unsigned short u) {
    unsigned int x = ((unsigned int)u) << 16;
    return __builtin_bit_cast(float, x);
}
__device__ __forceinline__ unsigned short f2bf(float f) {
    unsigned int x = __builtin_bit_cast(unsigned int, f);
    x = x + 0x7fffu + ((x >> 16) & 1u);   // round-to-nearest-even
    return (unsigned short)(x >> 16);
}

// async global->LDS, 16B per lane; LDS dest = wave-uniform base + lane*16
__device__ __forceinline__ void gload16(const void* gsrc, unsigned short* ldst) {
    __builtin_amdgcn_global_load_lds(
        (const __attribute__((address_space(1))) void*)gsrc,
        (__attribute__((address_space(3))) void*)ldst,
        16, 0, 0);
}

// ---------- ALL weight transposes in one launch ----------
// segments: [0,1024) Wq_sem  [1024,2048) Wq_geo  [2048,2304) Wk_sem
// [2304,2560) Wk_geo  [2560,3072) Wv  [3072,5120) Wo
__global__ void transpose_all(const float* __restrict__ Wq_sem,
                              const float* __restrict__ Wq_geo,
                              const float* __restrict__ Wk_sem,
                              const float* __restrict__ Wk_geo,
                              const float* __restrict__ Wv,
                              const float* __restrict__ Wo,
                              unsigned short* __restrict__ WcatT,
                              unsigned short* __restrict__ WoT) {
    __shared__ float tile[32][33];
    const int bid = blockIdx.x;
    const float* src; unsigned short* dst; int R, C, tiles_x, lt;
    if (bid < 1024)      { src = Wq_sem; dst = WcatT;                       R = 2048; C = 512;  tiles_x = 16; lt = bid; }
    else if (bid < 2048) { src = Wq_geo; dst = WcatT + (size_t)512  * 2048; R = 2048; C = 512;  tiles_x = 16; lt = bid - 1024; }
    else if (bid < 2304) { src = Wk_sem; dst = WcatT + (size_t)1024 * 2048; R = 2048; C = 128;  tiles_x = 4;  lt = bid - 2048; }
    else if (bid < 2560) { src = Wk_geo; dst = WcatT + (size_t)1152 * 2048; R = 2048; C = 128;  tiles_x = 4;  lt = bid - 2304; }
    else if (bid < 3072) { src = Wv;     dst = WcatT + (size_t)1280 * 2048; R = 2048; C = 256;  tiles_x = 8;  lt = bid - 2560; }
    else                 { src = Wo;     dst = WoT;                         R = 1024; C = 2048; tiles_x = 64; lt = bid - 3072; }
    const int ct = lt % tiles_x, rt = lt / tiles_x;
    const int tx = threadIdx.x, ty = threadIdx.y;
    #pragma unroll
    for (int i = ty; i < 32; i += 8)
        tile[i][tx] = src[(size_t)(rt * 32 + i) * C + ct * 32 + tx];
    __syncthreads();
    #pragma unroll
    for (int i = ty; i < 32; i += 8)
        dst[(size_t)(ct * 32 + i) * R + rt * 32 + tx] = f2bf(tile[tx][i]);
}

// ---------- 128x128 4-wave MFMA GEMM ----------
// C[M,N] = A[M,K] * BT[N,K]^T.  BK=32.  Both-sides LDS swizzle (measured
// conflict-free).  48 KB LDS, 3 blocks/CU, counted-or-drain vmcnt.
// MODE 0 (proj): A = x in FP32 (cvt fused: staged f32, cast to bf16 at
//   frag-read; identical RTNE rounding to the old cvt kernel).  Ring-2
//   (2 x (16KB A + 8KB B)), vmcnt(0)/tile.  Fused RoPE+pool epilogue.
// MODE 1 (Wo): bf16 A, ring-3 + vmcnt(4) (R8 config, measured 77 us).
template<int MODE>
__global__ __launch_bounds__(256, 3) void gemmP(
    const void* __restrict__ Ap,
    const unsigned short* __restrict__ BT,
    float* __restrict__ outF,
    unsigned short* __restrict__ qcat,
    unsigned short* __restrict__ kp,    // [bg][key][64]
    unsigned short* __restrict__ vt,    // [bg][d][KTOT]
    int M, int N, int K, int nbx)
{
    constexpr int RING = (MODE == 0) ? 2 : 3;
    constexpr int SLOT = (MODE == 0) ? 12288 : 8192;   // ushorts
    extern __shared__ __align__(16) unsigned short lds[];  // RING*SLOT

    const int tid = threadIdx.x;
    const int lane = tid & 63, w = tid >> 6;   // 4 waves: 2x2
    const int wr = w >> 1, wc = w & 1;
    const int l15 = lane & 15, lg = lane >> 4;

    // bijective XCD swizzle (gridDim.x % 8 == 0)
    const int cpx = gridDim.x >> 3;
    const int swz = (blockIdx.x & 7) * cpx + (blockIdx.x >> 3);
    const int bx = swz % nbx, by = swz / nbx;
    const int row0 = by * 128, col0 = bx * 128;

    // B staging (bf16): 512 chunks, 2/thread; involution (row>>1)&3
    const int scol = ((lane & 3) ^ ((lane >> 3) & 3)) * 8;
    const int srA = w * 16 + (lane >> 2);           // + j*64
    const unsigned short* Bg = BT + (size_t)col0 * K;

    // A staging MODE0 (f32): 1024 chunks, 4/thread; involution row&7
    const float* Agf = (const float*)Ap + (size_t)row0 * K;
    const int arow0 = tid >> 3;                     // + s4*32
    const int alc4  = ((tid & 7) ^ (arow0 & 7)) * 4;  // f32 col offset
    // A staging MODE1 (bf16): same as B
    const unsigned short* Agh = (const unsigned short*)Ap + (size_t)row0 * K;

    // frag-read offsets
    const int rdsw = (lg ^ ((l15 >> 1) & 3)) * 8;             // bf16 path
    const int boff = (wc * 64 + l15) * 32 + rdsw;             // + nf*512
    const int aoff_h = (wr * 64 + l15) * 32 + rdsw;           // MODE1 A
    const int aoff_f = (wr * 64 + l15) * 32;                  // MODE0 A (f32 units) + mf*512
    const int c0f = ((lg * 2)     ^ (l15 & 7)) * 4;           // f32 chunk offs
    const int c1f = ((lg * 2 + 1) ^ (l15 & 7)) * 4;

    const int NT = K >> 5;
    f32x4 acc[4][4] = {};

    auto stage = [&](int s, int kk) {
        unsigned short* sa = lds + s * SLOT;
        if (MODE == 0) {
            unsigned short* sb = sa + 8192;
            #pragma unroll
            for (int s4 = 0; s4 < 4; s4++)
                gload16(Agf + (size_t)(arow0 + s4 * 32) * K + kk + alc4,
                        sa + (s4 * 256 + w * 64) * 8);
            #pragma unroll
            for (int j = 0; j < 2; j++)
                gload16(Bg + (size_t)(srA + j * 64) * K + kk + scol,
                        sb + (j * 256 + w * 64) * 8);
        } else {
            unsigned short* sb = sa + 4096;
            #pragma unroll
            for (int j = 0; j < 2; j++) {
                gload16(Agh + (size_t)(srA + j * 64) * K + kk + scol,
                        sa + (j * 256 + w * 64) * 8);
                gload16(Bg + (size_t)(srA + j * 64) * K + kk + scol,
                        sb + (j * 256 + w * 64) * 8);
            }
        }
    };

    // prologue
    if (RING == 3) {
        stage(0, 0);
        stage(1, 32);
        asm volatile("s_waitcnt vmcnt(4)" ::: "memory");
    } else {
        stage(0, 0);
        asm volatile("s_waitcnt vmcnt(0)" ::: "memory");
    }

    int rs = 0;
    for (int t = 0; t < NT; ++t) {
        __builtin_amdgcn_s_barrier();            // write-slot readers done
        if (RING == 3) {
            if (t + 2 < NT) stage(rs == 0 ? 2 : rs - 1, (t + 2) << 5);
        } else {
            if (t + 1 < NT) stage(rs ^ 1, (t + 1) << 5);
        }

        bf16x8 af[4], bfr[4];
        if (MODE == 0) {
            const float* Asf = (const float*)(lds + rs * SLOT);
            const unsigned short* Bs_ = lds + rs * SLOT + 8192;
            #pragma unroll
            for (int mf = 0; mf < 4; mf++) {
                float4 f0 = *(const float4*)&Asf[aoff_f + mf * 512 + c0f];
                float4 f1 = *(const float4*)&Asf[aoff_f + mf * 512 + c1f];
                bf16x8 a;
                a[0] = (__bf16)f0.x; a[1] = (__bf16)f0.y;
                a[2] = (__bf16)f0.z; a[3] = (__bf16)f0.w;
                a[4] = (__bf16)f1.x; a[5] = (__bf16)f1.y;
                a[6] = (__bf16)f1.z; a[7] = (__bf16)f1.w;
                af[mf] = a;
            }
            #pragma unroll
            for (int nf = 0; nf < 4; nf++)
                bfr[nf] = __builtin_bit_cast(bf16x8, *(const uint4*)&Bs_[boff + nf * 512]);
        } else {
            const unsigned short* As_ = lds + rs * SLOT;
            const unsigned short* Bs_ = As_ + 4096;
            #pragma unroll
            for (int mf = 0; mf < 4; mf++)
                af[mf] = __builtin_bit_cast(bf16x8, *(const uint4*)&As_[aoff_h + mf * 512]);
            #pragma unroll
            for (int nf = 0; nf < 4; nf++)
                bfr[nf] = __builtin_bit_cast(bf16x8, *(const uint4*)&Bs_[boff + nf * 512]);
        }

        __builtin_amdgcn_s_setprio(1);
        #pragma unroll
        for (int mf = 0; mf < 4; mf++)
            #pragma unroll
            for (int nf = 0; nf < 4; nf++)
                acc[mf][nf] = __builtin_amdgcn_mfma_f32_16x16x32_bf16(
                                  af[mf], bfr[nf], acc[mf][nf], 0, 0, 0);
        __builtin_amdgcn_s_setprio(0);

        if (RING == 3) {
            if (t + 2 < NT) asm volatile("s_waitcnt vmcnt(4)" ::: "memory");
            else            asm volatile("s_waitcnt vmcnt(0)" ::: "memory");
            rs = (rs == 2) ? 0 : rs + 1;
        } else {
            if (t + 1 < NT) asm volatile("s_waitcnt vmcnt(0)" ::: "memory");
            rs ^= 1;
        }
    }

    // ---- epilogue ----
    if (MODE == 1) {
        #pragma unroll
        for (int mf = 0; mf < 4; mf++)
            #pragma unroll
            for (int nf = 0; nf < 4; nf++)
                #pragma unroll
                for (int r = 0; r < 4; r++) {
                    int row = row0 + wr * 64 + mf * 16 + lg * 4 + r;
                    int col = col0 + wc * 64 + nf * 16 + l15;
                    outF[(size_t)row * N + col] = acc[mf][nf][r];
                }
    } else {
        const int cspan = col0 + wc * 64;       // wave col base (64-aligned)
        const int tbase = row0 & 4095;          // t of tile row 0 (b uniform)
        const int bq = row0 >> 12;

        // RoPE on geo spans: pair (d, d+16) == (nf, nf+1) in-fragment
        if ((cspan >= 512 && cspan < 1024) || (cspan >= 1152 && cspan < 1280)) {
            const float invf = exp2f(-(float)l15 * 0.8304820237218406f);
            #pragma unroll
            for (int mf = 0; mf < 4; mf++) {
                #pragma unroll
                for (int r = 0; r < 4; r++) {
                    float s, c;
                    sincosf((float)(tbase + wr*64 + mf*16 + lg*4 + r) * invf, &s, &c);
                    float a0 = acc[mf][0][r], a1 = acc[mf][1][r];
                    acc[mf][0][r] = a0 * c - a1 * s;
                    acc[mf][1][r] = a1 * c + a0 * s;
                    float a2 = acc[mf][2][r], a3 = acc[mf][3][r];
                    acc[mf][2][r] = a2 * c - a3 * s;
                    acc[mf][3][r] = a3 * c + a2 * s;
                }
            }
        }

        if (cspan < 1024) {
            // ---- Q -> qcat [b][h][t][64] ----
            #pragma unroll
            for (int nf = 0; nf < 4; nf++) {
                int col = cspan + nf * 16 + l15;
                int h = (col < 512) ? (col >> 5) : ((col - 512) >> 5);
                int d = (col < 512) ? (col & 31) : (32 + (col & 31));
                unsigned short* qb =
                    qcat + (((size_t)(bq * 16 + h)) * 4096 + tbase) * 64 + d;
                #pragma unroll
                for (int mf = 0; mf < 4; mf++)
                    #pragma unroll
                    for (int r = 0; r < 4; r++)
                        qb[(size_t)(wr*64 + mf*16 + lg*4 + r) * 64] =
                            f2bf(acc[mf][nf][r]);
            }
        } else if (tbase >= REMOTE) {
            // ---- local K/V rows -> full-res keys 48..1071 ----
            #pragma unroll
            for (int nf = 0; nf < 4; nf++) {
                int col = cspan + nf * 16 + l15;
                #pragma unroll
                for (int mf = 0; mf < 4; mf++)
                    #pragma unroll
                    for (int r = 0; r < 4; r++) {
                        int key = tbase + wr*64 + mf*16 + lg*4 + r - 3024;
                        unsigned short hv = f2bf(acc[mf][nf][r]);
                        if (col < 1280) {
                            int g, dk;
                            if (col < 1152) { g = (col - 1024) >> 5; dk = col & 31; }
                            else            { g = (col - 1152) >> 5; dk = 32 + (col & 31); }
                            kp[(((size_t)(bq*4 + g)) * KTOT + key) * 64 + dk] = hv;
                        } else {
                            int g = (col - 1280) >> 6, dv = col & 63;
                            vt[(((size_t)(bq*4 + g)) * 64 + dv) * KTOT + key] = hv;
                        }
                    }
            }
        } else {
            // ---- remote K/V rows -> mem-block pooled (wr half = one block) ----
            #pragma unroll
            for (int nf = 0; nf < 4; nf++) {
                float ps = 0.f;
                #pragma unroll
                for (int mf = 0; mf < 4; mf++)
                    #pragma unroll
                    for (int r = 0; r < 4; r++) ps += acc[mf][nf][r];
                ps += __shfl_xor(ps, 16);
                ps += __shfl_xor(ps, 32);
                if (lane < 16) {
                    int col = cspan + nf * 16 + l15;
                    int key = (tbase >> 6) + wr;
                    unsigned short hv = f2bf(ps * (1.f / 64.f));
                    if (col < 1280) {
                        int g, dk;
                        if (col < 1152) { g = (col - 1024) >> 5; dk = col & 31; }
                        else            { g = (col - 1152) >> 5; dk = 32 + (col & 31); }
                        kp[(((size_t)(bq*4 + g)) * KTOT + key) * 64 + dk] = hv;
                    } else {
                        int g = (col - 1280) >> 6, dv = col & 63;
                        vt[(((size_t)(bq*4 + g)) * 64 + dv) * KTOT + key] = hv;
                    }
                }
            }
        }
    }
}

// ---------- MFMA flash attention, wave-independent (NO barriers) ----------
__global__ __launch_bounds__(256) void attn_fwd(
    const unsigned short* __restrict__ qcat,
    const unsigned short* __restrict__ kp,   // [bg][key][64]
    const unsigned short* __restrict__ vt,   // [bg][d][KTOT]
    const float* __restrict__ ls,
    unsigned short* __restrict__ attn_out)
{
    __shared__ unsigned short Pl[4][32][72];   // per-wave P tile (bf16)

    const int tid = threadIdx.x;
    const int lane = tid & 63, w = tid >> 6;
    const int l15 = lane & 15, lg = lane >> 4;

    const int wid = blockIdx.x * 4 + w;        // 0..4095
    const int hb = wid & 31;
    const int iu = wid >> 5;                   // schedule slot 0..127
    int i;
    if (iu < 32)       i = 127 - iu;
    else if (iu == 32) i = 0;
    else if (iu == 33) i = 1;
    else               i = iu - 32;
    const int h = hb & 15, b = hb >> 4, g = h >> 2;
    const int q0 = i * 32;

    int ktmax;
    if (q0 < 64) ktmax = NTILES;               // uniform rows: all keys
    else {
        int lastkey = q0 + 31 - 3024;          // max valid local key index
        ktmax = (lastkey < NBLK) ? 1 : (lastkey / 64 + 1);
    }

    const float sc = __expf(ls[h]) * 0.17677669529663687f;   // exp(ls)/sqrt(32)

    bf16x8 aq[2][2];
    const unsigned short* qbase = qcat + (((size_t)(b * 16 + h)) * T_ + q0) * 64;
    #pragma unroll
    for (int rf = 0; rf < 2; rf++)
        #pragma unroll
        for (int kh = 0; kh < 2; kh++)
            aq[rf][kh] = __builtin_bit_cast(bf16x8,
                *(const uint4*)(qbase + (size_t)(rf*16 + l15)*64 + kh*32 + lg*8));

    float m[2][4], lrun[2][4];
    #pragma unroll
    for (int rf = 0; rf < 2; rf++)
        #pragma unroll
        for (int r = 0; r < 4; r++) { m[rf][r] = -1e9f; lrun[rf][r] = 0.f; }
    f32x4 oacc[2][4] = {};

    const unsigned short* kbase = kp + ((size_t)(b * 4 + g)) * KTOT * 64;
    const unsigned short* vbase = vt + ((size_t)(b * 4 + g)) * 64 * KTOT;

    for (int kt = 0; kt < ktmax; kt++) {
        const int kb = kt * 64;

        bf16x8 bk[4][2];
        #pragma unroll
        for (int nf = 0; nf < 4; nf++) {
            int krow = kb + nf*16 + l15;
            int krc = krow < KTOT ? krow : KTOT - 1;     // clamp (masked later)
            #pragma unroll
            for (int kh = 0; kh < 2; kh++)
                bk[nf][kh] = __builtin_bit_cast(bf16x8,
                    *(const uint4*)(kbase + (size_t)krc * 64 + kh*32 + lg*8));
        }

        f32x4 s[2][4] = {};
        #pragma unroll
        for (int rf = 0; rf < 2; rf++)
            #pragma unroll
            for (int nf = 0; nf < 4; nf++)
                #pragma unroll
                for (int kh = 0; kh < 2; kh++)
                    s[rf][nf] = __builtin_amdgcn_mfma_f32_16x16x32_bf16(
                                    aq[rf][kh], bk[nf][kh], s[rf][nf], 0, 0, 0);

        bf16x8 bv[4][2];
        #pragma unroll
        for (int nfv = 0; nfv < 4; nfv++)
            #pragma unroll
            for (int kh = 0; kh < 2; kh++) {
                int kc = kb + kh*32 + lg*8;
                int kcc = (kc + 8 <= KTOT) ? kc : KTOT - 8;  // clamp (P=0 there)
                bv[nfv][kh] = __builtin_bit_cast(bf16x8,
                    *(const uint4*)(vbase + (size_t)(nfv*16 + l15) * KTOT + kcc));
            }

        #pragma unroll
        for (int rf = 0; rf < 2; rf++) {
            #pragma unroll
            for (int r = 0; r < 4; r++) {
                const int qpos = q0 + rf*16 + lg*4 + r;
                float vals[4];
                float tmax = -INFINITY;
                #pragma unroll
                for (int nf = 0; nf < 4; nf++) {
                    int key = kb + nf*16 + l15;
                    float v = s[rf][nf][r] * sc;
                    int kpos = (key < NBLK) ? key * 64 + 63 : 3024 + key;
                    v = (key < KTOT) ? ((kpos <= qpos) ? v : -1e9f) : -INFINITY;
                    vals[nf] = v;
                    tmax = fmaxf(tmax, v);
                }
                #pragma unroll
                for (int d = 1; d < 16; d <<= 1)
                    tmax = fmaxf(tmax, __shfl_xor(tmax, d));
                float mn = fmaxf(m[rf][r], tmax);
                float scl = __expf(m[rf][r] - mn);
                m[rf][r] = mn;
                float rs = 0.f;
                #pragma unroll
                for (int nf = 0; nf < 4; nf++) {
                    unsigned short pb = f2bf(__expf(vals[nf] - mn));
                    rs += bf2f(pb);          // sum the ROUNDED p: exact convex comb
                    Pl[w][rf*16 + lg*4 + r][nf*16 + l15] = pb;
                }
                #pragma unroll
                for (int d = 1; d < 16; d <<= 1)
                    rs += __shfl_xor(rs, d);
                lrun[rf][r] = lrun[rf][r] * scl + rs;
                #pragma unroll
                for (int nfv = 0; nfv < 4; nfv++)
                    oacc[rf][nfv][r] *= scl;
            }
        }

        #pragma unroll
        for (int rf = 0; rf < 2; rf++) {
            bf16x8 pa[2];
            #pragma unroll
            for (int kh = 0; kh < 2; kh++)
                pa[kh] = __builtin_bit_cast(bf16x8,
                    *(const uint4*)&Pl[w][rf*16 + l15][kh*32 + lg*8]);
            #pragma unroll
            for (int nfv = 0; nfv < 4; nfv++)
                #pragma unroll
                for (int kh = 0; kh < 2; kh++)
                    oacc[rf][nfv] = __builtin_amdgcn_mfma_f32_16x16x32_bf16(
                                        pa[kh], bv[nfv][kh], oacc[rf][nfv], 0, 0, 0);
        }
    }

    #pragma unroll
    for (int rf = 0; rf < 2; rf++) {
        #pragma unroll
        for (int r = 0; r < 4; r++) {
            float inv = 1.f / lrun[rf][r];
            int q = q0 + rf*16 + lg*4 + r;
            size_t obase = ((size_t)(b * T_ + q)) * 1024 + h * 64;
            #pragma unroll
            for (int nfv = 0; nfv < 4; nfv++)
                attn_out[obase + nfv*16 + l15] = f2bf(oacc[rf][nfv][r] * inv);
        }
    }
}

// ---------- host launch ----------
extern "C" void kernel_launch(void* const* d_in, const int* in_sizes, int n_in,
                              void* d_out, int out_size, void* d_ws, size_t ws_size,
                              hipStream_t stream) {
    const float* x      = (const float*)d_in[0];
    const float* Wq_sem = (const float*)d_in[1];
    const float* Wk_sem = (const float*)d_in[2];
    const float* Wq_geo = (const float*)d_in[3];
    const float* Wk_geo = (const float*)d_in[4];
    const float* Wv     = (const float*)d_in[5];
    const float* Wo     = (const float*)d_in[6];
    const float* ls     = (const float*)d_in[7];

    char* w = (char*)d_ws;
    auto alloc = [&](size_t bytes) {
        char* p = w;
        w += (bytes + 255) & ~(size_t)255;
        return p;
    };
    unsigned short* WcatT = (unsigned short*)alloc((size_t)1536 * 2048 * 2);
    unsigned short* WoT   = (unsigned short*)alloc((size_t)2048 * 1024 * 2);
    unsigned short* qcat  = (unsigned short*)alloc((size_t)2 * 16 * 4096 * 64 * 2);
    unsigned short* kp    = (unsigned short*)alloc((size_t)2 * 4 * 1072 * 64 * 2);
    unsigned short* vt    = (unsigned short*)alloc((size_t)2 * 4 * 1072 * 64 * 2);
    unsigned short* aout  = (unsigned short*)alloc((size_t)8192 * 1024 * 2);

    hipFuncSetAttribute(reinterpret_cast<const void*>(&gemmP<0>),
                        hipFuncAttributeMaxDynamicSharedMemorySize, 49152);
    hipFuncSetAttribute(reinterpret_cast<const void*>(&gemmP<1>),
                        hipFuncAttributeMaxDynamicSharedMemorySize, 49152);

    // 1) all weight transposes in ONE launch
    transpose_all<<<5120, dim3(32, 8), 0, stream>>>(
        Wq_sem, Wq_geo, Wk_sem, Wk_geo, Wv, Wo, WcatT, WoT);

    // 2) fused projection GEMM (cvt + RoPE + pooling fused) -> qcat / kp / vt
    //    A = x in f32; 768 blocks = 3/CU single round
    gemmP<0><<<768, 256, 49152, stream>>>(
        x, WcatT, nullptr, qcat, kp, vt, 8192, 1536, 2048, 12);

    // 3) wave-independent MFMA flash attention
    attn_fwd<<<dim3(1024), 256, 0, stream>>>(qcat, kp, vt, ls, aout);

    // 4) output projection -> d_out (fp32); ring-3 (R8 config)
    gemmP<1><<<1024, 256, 49152, stream>>>(
        aout, WoT, (float*)d_out, nullptr, nullptr, nullptr, 8192, 2048, 1024, 16);
}

// Round 13
// 185.285 us; speedup vs baseline: 1.1590x; 1.0070x over previous
//
#include <hip/hip_runtime.h>
#include <math.h>

// ---------- constants ----------
#define B_  2
#define T_  4096
#define DM  2048
#define H_  16
#define HKV 4
#define DV_ 64
#define MB_ 64
#define LW_ 1024
#define REMOTE 3072     // T - LW
#define NBLK 48         // REMOTE/MB
#define KTOT 1072       // NBLK + LW
#define NTILES 17       // ceil(1072/64)

typedef __bf16 bf16x8 __attribute__((ext_vector_type(8)));
typedef float  f32x4  __attribute__((ext_vector_type(4)));

__device__ __forceinline__ float bf2f(unsigned short u) {
    unsigned int x = ((unsigned int)u) << 16;
    return __builtin_bit_cast(float, x);
}
__device__ __forceinline__ unsigned short f2bf(float f) {
    unsigned int x = __builtin_bit_cast(unsigned int, f);
    x = x + 0x7fffu + ((x >> 16) & 1u);   // round-to-nearest-even
    return (unsigned short)(x >> 16);
}

// async global->LDS, 16B per lane; LDS dest = wave-uniform base + lane*16
__device__ __forceinline__ void gload16(const void* gsrc, unsigned short* ldst) {
    __builtin_amdgcn_global_load_lds(
        (const __attribute__((address_space(1))) void*)gsrc,
        (__attribute__((address_space(3))) void*)ldst,
        16, 0, 0);
}

// ---------- ALL weight transposes in one launch ----------
__global__ void transpose_all(const float* __restrict__ Wq_sem,
                              const float* __restrict__ Wq_geo,
                              const float* __restrict__ Wk_sem,
                              const float* __restrict__ Wk_geo,
                              const float* __restrict__ Wv,
                              const float* __restrict__ Wo,
                              unsigned short* __restrict__ WcatT,
                              unsigned short* __restrict__ WoT) {
    __shared__ float tile[32][33];
    const int bid = blockIdx.x;
    const float* src; unsigned short* dst; int R, C, tiles_x, lt;
    if (bid < 1024)      { src = Wq_sem; dst = WcatT;                       R = 2048; C = 512;  tiles_x = 16; lt = bid; }
    else if (bid < 2048) { src = Wq_geo; dst = WcatT + (size_t)512  * 2048; R = 2048; C = 512;  tiles_x = 16; lt = bid - 1024; }
    else if (bid < 2304) { src = Wk_sem; dst = WcatT + (size_t)1024 * 2048; R = 2048; C = 128;  tiles_x = 4;  lt = bid - 2048; }
    else if (bid < 2560) { src = Wk_geo; dst = WcatT + (size_t)1152 * 2048; R = 2048; C = 128;  tiles_x = 4;  lt = bid - 2304; }
    else if (bid < 3072) { src = Wv;     dst = WcatT + (size_t)1280 * 2048; R = 2048; C = 256;  tiles_x = 8;  lt = bid - 2560; }
    else                 { src = Wo;     dst = WoT;                         R = 1024; C = 2048; tiles_x = 64; lt = bid - 3072; }
    const int ct = lt % tiles_x, rt = lt / tiles_x;
    const int tx = threadIdx.x, ty = threadIdx.y;
    #pragma unroll
    for (int i = ty; i < 32; i += 8)
        tile[i][tx] = src[(size_t)(rt * 32 + i) * C + ct * 32 + tx];
    __syncthreads();
    #pragma unroll
    for (int i = ty; i < 32; i += 8)
        dst[(size_t)(ct * 32 + i) * R + rt * 32 + tx] = f2bf(tile[tx][i]);
}

// ---------- 128x128 4-wave MFMA GEMM, ring-3 LDS (16KB slots, 48KB) -------
// C[M,N] = A[M,K] * BT[N,K]^T.  BK=32.  Verified bf16 LDS layout both
// operands (swizzle involution (row>>1)&3 — measured conflict-free).
// MODE 0 (proj): A = x in FP32, cvt fused via T14 async reg-stage:
//   iter t: issue 4 f32x4 loads (tile t+2) -> regs; bottom: cvt + swizzled
//   ds_write_b128 into slot(t+1).  B via gload_lds (tile t+2).  vmcnt(6)
//   + lgkmcnt(0) + barrier per iter.  Fused RoPE+pool epilogue.
// MODE 1 (Wo): both operands gload_lds, counted vmcnt(4) (R8 config).
template<int MODE>
__global__ __launch_bounds__(256, 3) void gemmP(
    const void* __restrict__ Ap,
    const unsigned short* __restrict__ BT,
    float* __restrict__ outF,
    unsigned short* __restrict__ qcat,
    unsigned short* __restrict__ kp,    // [bg][key][64]
    unsigned short* __restrict__ vt,    // [bg][d][KTOT]
    int M, int N, int K, int nbx)
{
    extern __shared__ __align__(16) unsigned short lds[];  // 3*8192 ushorts

    const int tid = threadIdx.x;
    const int lane = tid & 63, w = tid >> 6;   // 4 waves: 2x2
    const int wr = w >> 1, wc = w & 1;
    const int l15 = lane & 15, lg = lane >> 4;

    // bijective XCD swizzle (gridDim.x % 8 == 0)
    const int cpx = gridDim.x >> 3;
    const int swz = (blockIdx.x & 7) * cpx + (blockIdx.x >> 3);
    const int bx = swz % nbx, by = swz / nbx;
    const int row0 = by * 128, col0 = bx * 128;

    // bf16 gload staging geometry (chunks {tid, tid+256}, involution (r>>1)&3)
    const int scol = ((lane & 3) ^ ((lane >> 3) & 3)) * 8;
    const int srA = w * 16 + (lane >> 2);           // + j*64
    const unsigned short* Bg = BT + (size_t)col0 * K;
    const unsigned short* Agh = (const unsigned short*)Ap + (size_t)row0 * K;

    // MODE 0 A reg-staging: thread owns chunks (ar0, ac) and (ar1, ac)
    const int ar0 = tid >> 2, ar1 = ar0 + 64, ac = tid & 3;
    const int agc0 = (ac ^ ((ar0 >> 1) & 3)) * 8;   // global f32 col offset
    const int agc1 = (ac ^ ((ar1 >> 1) & 3)) * 8;
    const float* Axf = (const float*)Ap + (size_t)row0 * K;

    // frag-read offsets (verified conflict-free)
    const int rdsw = (lg ^ ((l15 >> 1) & 3)) * 8;
    const int aoff = (wr * 64 + l15) * 32 + rdsw;   // + mf*512
    const int boff = (wc * 64 + l15) * 32 + rdsw;   // + nf*512

    const int NT = K >> 5;
    f32x4 acc[4][4] = {};

    auto stageB = [&](int s, int kk) {
        unsigned short* sb = lds + s * 8192 + 4096;
        #pragma unroll
        for (int j = 0; j < 2; j++)
            gload16(Bg + (size_t)(srA + j * 64) * K + kk + scol,
                    sb + (j * 256 + w * 64) * 8);
    };
    auto stageAB = [&](int s, int kk) {      // MODE 1: both via gload_lds
        unsigned short* sa = lds + s * 8192;
        unsigned short* sb = sa + 4096;
        #pragma unroll
        for (int j = 0; j < 2; j++) {
            gload16(Agh + (size_t)(srA + j * 64) * K + kk + scol,
                    sa + (j * 256 + w * 64) * 8);
            gload16(Bg + (size_t)(srA + j * 64) * K + kk + scol,
                    sb + (j * 256 + w * 64) * 8);
        }
    };
    auto issueA = [&](float4* ra, int kk) {
        ra[0] = *(const float4*)&Axf[(size_t)ar0 * K + kk + agc0];
        ra[1] = *(const float4*)&Axf[(size_t)ar0 * K + kk + agc0 + 4];
        ra[2] = *(const float4*)&Axf[(size_t)ar1 * K + kk + agc1];
        ra[3] = *(const float4*)&Axf[(size_t)ar1 * K + kk + agc1 + 4];
    };
    auto writeA = [&](int s, const float4* ra) {
        unsigned short* sa = lds + s * 8192;
        bf16x8 v0, v1;
        v0[0] = (__bf16)ra[0].x; v0[1] = (__bf16)ra[0].y;
        v0[2] = (__bf16)ra[0].z; v0[3] = (__bf16)ra[0].w;
        v0[4] = (__bf16)ra[1].x; v0[5] = (__bf16)ra[1].y;
        v0[6] = (__bf16)ra[1].z; v0[7] = (__bf16)ra[1].w;
        v1[0] = (__bf16)ra[2].x; v1[1] = (__bf16)ra[2].y;
        v1[2] = (__bf16)ra[2].z; v1[3] = (__bf16)ra[2].w;
        v1[4] = (__bf16)ra[3].x; v1[5] = (__bf16)ra[3].y;
        v1[6] = (__bf16)ra[3].z; v1[7] = (__bf16)ra[3].w;
        *(uint4*)&sa[ar0 * 32 + ac * 8] = __builtin_bit_cast(uint4, v0);
        *(uint4*)&sa[ar1 * 32 + ac * 8] = __builtin_bit_cast(uint4, v1);
    };

    #define FRAGS_MFMA(rs_)                                                     \
        {                                                                       \
            const unsigned short* As_ = lds + (rs_) * 8192;                     \
            const unsigned short* Bs_ = As_ + 4096;                             \
            bf16x8 af[4], bfr[4];                                               \
            _Pragma("unroll")                                                   \
            for (int mf = 0; mf < 4; mf++)                                      \
                af[mf] = __builtin_bit_cast(bf16x8,                             \
                    *(const uint4*)&As_[aoff + mf * 512]);                      \
            _Pragma("unroll")                                                   \
            for (int nf = 0; nf < 4; nf++)                                      \
                bfr[nf] = __builtin_bit_cast(bf16x8,                            \
                    *(const uint4*)&Bs_[boff + nf * 512]);                      \
            __builtin_amdgcn_s_setprio(1);                                      \
            _Pragma("unroll")                                                   \
            for (int mf = 0; mf < 4; mf++)                                      \
                _Pragma("unroll")                                               \
                for (int nf = 0; nf < 4; nf++)                                  \
                    acc[mf][nf] = __builtin_amdgcn_mfma_f32_16x16x32_bf16(      \
                        af[mf], bfr[nf], acc[mf][nf], 0, 0, 0);                 \
            __builtin_amdgcn_s_setprio(0);                                      \
        }

    if (MODE == 0) {
        // ---- prologue: B(0),B(1) async; A(0) write; A(1) in regs ----
        stageB(0, 0);
        stageB(1, 32);
        __builtin_amdgcn_sched_barrier(0);
        float4 rA[4], rB[4];
        issueA(rA, 0);
        issueA(rB, 32);
        writeA(0, rA);                         // waits A(0) => B(0),B(1) retired
        asm volatile("s_waitcnt lgkmcnt(0)" ::: "memory");
        __builtin_amdgcn_s_barrier();

        int rs = 0;
        for (int t = 0; t < NT; t += 2) {
            // ---- even: read tile t; issue t+2; write A(t+1) from rB ----
            {
                if (t + 2 < NT) {
                    stageB(rs == 0 ? 2 : rs - 1, (t + 2) << 5);
                    __builtin_amdgcn_sched_barrier(0);   // B before A in FIFO
                    issueA(rA, (t + 2) << 5);
                }
                FRAGS_MFMA(rs);
                int s1 = (rs == 2) ? 0 : rs + 1;
                writeA(s1, rB);                 // waits A(t+1) => B(t+1) retired
                asm volatile("s_waitcnt vmcnt(6)" ::: "memory");
                asm volatile("s_waitcnt lgkmcnt(0)" ::: "memory");
                __builtin_amdgcn_s_barrier();
                rs = s1;
            }
            // ---- odd: read tile t+1; issue t+3; write A(t+2) from rA ----
            {
                if (t + 3 < NT) {
                    stageB(rs == 0 ? 2 : rs - 1, (t + 3) << 5);
                    __builtin_amdgcn_sched_barrier(0);
                    issueA(rB, (t + 3) << 5);
                }
                FRAGS_MFMA(rs);
                int s1 = (rs == 2) ? 0 : rs + 1;
                if (t + 2 < NT) writeA(s1, rA);
                asm volatile("s_waitcnt vmcnt(6)" ::: "memory");
                asm volatile("s_waitcnt lgkmcnt(0)" ::: "memory");
                __builtin_amdgcn_s_barrier();
                rs = s1;
            }
        }
    } else {
        // ---- MODE 1: R8 ring-3 config, both operands gload_lds ----
        stageAB(0, 0);
        stageAB(1, 32);
        asm volatile("s_waitcnt vmcnt(4)" ::: "memory");
        int rs = 0;
        for (int t = 0; t < NT; ++t) {
            __builtin_amdgcn_s_barrier();
            if (t + 2 < NT) stageAB(rs == 0 ? 2 : rs - 1, (t + 2) << 5);
            FRAGS_MFMA(rs);
            if (t + 2 < NT) asm volatile("s_waitcnt vmcnt(4)" ::: "memory");
            else            asm volatile("s_waitcnt vmcnt(0)" ::: "memory");
            rs = (rs == 2) ? 0 : rs + 1;
        }
    }
    #undef FRAGS_MFMA

    // ---- epilogue ----
    if (MODE == 1) {
        #pragma unroll
        for (int mf = 0; mf < 4; mf++)
            #pragma unroll
            for (int nf = 0; nf < 4; nf++)
                #pragma unroll
                for (int r = 0; r < 4; r++) {
                    int row = row0 + wr * 64 + mf * 16 + lg * 4 + r;
                    int col = col0 + wc * 64 + nf * 16 + l15;
                    outF[(size_t)row * N + col] = acc[mf][nf][r];
                }
    } else {
        const int cspan = col0 + wc * 64;       // wave col base (64-aligned)
        const int tbase = row0 & 4095;          // t of tile row 0 (b uniform)
        const int bq = row0 >> 12;

        // RoPE on geo spans: pair (d, d+16) == (nf, nf+1) in-fragment
        if ((cspan >= 512 && cspan < 1024) || (cspan >= 1152 && cspan < 1280)) {
            const float invf = exp2f(-(float)l15 * 0.8304820237218406f);
            #pragma unroll
            for (int mf = 0; mf < 4; mf++) {
                #pragma unroll
                for (int r = 0; r < 4; r++) {
                    float s, c;
                    sincosf((float)(tbase + wr*64 + mf*16 + lg*4 + r) * invf, &s, &c);
                    float a0 = acc[mf][0][r], a1 = acc[mf][1][r];
                    acc[mf][0][r] = a0 * c - a1 * s;
                    acc[mf][1][r] = a1 * c + a0 * s;
                    float a2 = acc[mf][2][r], a3 = acc[mf][3][r];
                    acc[mf][2][r] = a2 * c - a3 * s;
                    acc[mf][3][r] = a3 * c + a2 * s;
                }
            }
        }

        if (cspan < 1024) {
            // ---- Q -> qcat [b][h][t][64] ----
            #pragma unroll
            for (int nf = 0; nf < 4; nf++) {
                int col = cspan + nf * 16 + l15;
                int h = (col < 512) ? (col >> 5) : ((col - 512) >> 5);
                int d = (col < 512) ? (col & 31) : (32 + (col & 31));
                unsigned short* qb =
                    qcat + (((size_t)(bq * 16 + h)) * 4096 + tbase) * 64 + d;
                #pragma unroll
                for (int mf = 0; mf < 4; mf++)
                    #pragma unroll
                    for (int r = 0; r < 4; r++)
                        qb[(size_t)(wr*64 + mf*16 + lg*4 + r) * 64] =
                            f2bf(acc[mf][nf][r]);
            }
        } else if (tbase >= REMOTE) {
            // ---- local K/V rows -> full-res keys 48..1071 ----
            #pragma unroll
            for (int nf = 0; nf < 4; nf++) {
                int col = cspan + nf * 16 + l15;
                #pragma unroll
                for (int mf = 0; mf < 4; mf++)
                    #pragma unroll
                    for (int r = 0; r < 4; r++) {
                        int key = tbase + wr*64 + mf*16 + lg*4 + r - 3024;
                        unsigned short hv = f2bf(acc[mf][nf][r]);
                        if (col < 1280) {
                            int g, dk;
                            if (col < 1152) { g = (col - 1024) >> 5; dk = col & 31; }
                            else            { g = (col - 1152) >> 5; dk = 32 + (col & 31); }
                            kp[(((size_t)(bq*4 + g)) * KTOT + key) * 64 + dk] = hv;
                        } else {
                            int g = (col - 1280) >> 6, dv = col & 63;
                            vt[(((size_t)(bq*4 + g)) * 64 + dv) * KTOT + key] = hv;
                        }
                    }
            }
        } else {
            // ---- remote K/V rows -> mem-block pooled (wr half = one block) ----
            #pragma unroll
            for (int nf = 0; nf < 4; nf++) {
                float ps = 0.f;
                #pragma unroll
                for (int mf = 0; mf < 4; mf++)
                    #pragma unroll
                    for (int r = 0; r < 4; r++) ps += acc[mf][nf][r];
                ps += __shfl_xor(ps, 16);
                ps += __shfl_xor(ps, 32);
                if (lane < 16) {
                    int col = cspan + nf * 16 + l15;
                    int key = (tbase >> 6) + wr;
                    unsigned short hv = f2bf(ps * (1.f / 64.f));
                    if (col < 1280) {
                        int g, dk;
                        if (col < 1152) { g = (col - 1024) >> 5; dk = col & 31; }
                        else            { g = (col - 1152) >> 5; dk = 32 + (col & 31); }
                        kp[(((size_t)(bq*4 + g)) * KTOT + key) * 64 + dk] = hv;
                    } else {
                        int g = (col - 1280) >> 6, dv = col & 63;
                        vt[(((size_t)(bq*4 + g)) * 64 + dv) * KTOT + key] = hv;
                    }
                }
            }
        }
    }
}

// ---------- MFMA flash attention, wave-independent (NO barriers) ----------
__global__ __launch_bounds__(256) void attn_fwd(
    const unsigned short* __restrict__ qcat,
    const unsigned short* __restrict__ kp,   // [bg][key][64]
    const unsigned short* __restrict__ vt,   // [bg][d][KTOT]
    const float* __restrict__ ls,
    unsigned short* __restrict__ attn_out)
{
    __shared__ unsigned short Pl[4][32][72];   // per-wave P tile (bf16)

    const int tid = threadIdx.x;
    const int lane = tid & 63, w = tid >> 6;
    const int l15 = lane & 15, lg = lane >> 4;

    const int wid = blockIdx.x * 4 + w;        // 0..4095
    const int hb = wid & 31;
    const int iu = wid >> 5;                   // schedule slot 0..127
    int i;
    if (iu < 32)       i = 127 - iu;
    else if (iu == 32) i = 0;
    else if (iu == 33) i = 1;
    else               i = iu - 32;
    const int h = hb & 15, b = hb >> 4, g = h >> 2;
    const int q0 = i * 32;

    int ktmax;
    if (q0 < 64) ktmax = NTILES;               // uniform rows: all keys
    else {
        int lastkey = q0 + 31 - 3024;          // max valid local key index
        ktmax = (lastkey < NBLK) ? 1 : (lastkey / 64 + 1);
    }

    const float sc = __expf(ls[h]) * 0.17677669529663687f;   // exp(ls)/sqrt(32)

    bf16x8 aq[2][2];
    const unsigned short* qbase = qcat + (((size_t)(b * 16 + h)) * T_ + q0) * 64;
    #pragma unroll
    for (int rf = 0; rf < 2; rf++)
        #pragma unroll
        for (int kh = 0; kh < 2; kh++)
            aq[rf][kh] = __builtin_bit_cast(bf16x8,
                *(const uint4*)(qbase + (size_t)(rf*16 + l15)*64 + kh*32 + lg*8));

    float m[2][4], lrun[2][4];
    #pragma unroll
    for (int rf = 0; rf < 2; rf++)
        #pragma unroll
        for (int r = 0; r < 4; r++) { m[rf][r] = -1e9f; lrun[rf][r] = 0.f; }
    f32x4 oacc[2][4] = {};

    const unsigned short* kbase = kp + ((size_t)(b * 4 + g)) * KTOT * 64;
    const unsigned short* vbase = vt + ((size_t)(b * 4 + g)) * 64 * KTOT;

    for (int kt = 0; kt < ktmax; kt++) {
        const int kb = kt * 64;

        bf16x8 bk[4][2];
        #pragma unroll
        for (int nf = 0; nf < 4; nf++) {
            int krow = kb + nf*16 + l15;
            int krc = krow < KTOT ? krow : KTOT - 1;     // clamp (masked later)
            #pragma unroll
            for (int kh = 0; kh < 2; kh++)
                bk[nf][kh] = __builtin_bit_cast(bf16x8,
                    *(const uint4*)(kbase + (size_t)krc * 64 + kh*32 + lg*8));
        }

        f32x4 s[2][4] = {};
        #pragma unroll
        for (int rf = 0; rf < 2; rf++)
            #pragma unroll
            for (int nf = 0; nf < 4; nf++)
                #pragma unroll
                for (int kh = 0; kh < 2; kh++)
                    s[rf][nf] = __builtin_amdgcn_mfma_f32_16x16x32_bf16(
                                    aq[rf][kh], bk[nf][kh], s[rf][nf], 0, 0, 0);

        bf16x8 bv[4][2];
        #pragma unroll
        for (int nfv = 0; nfv < 4; nfv++)
            #pragma unroll
            for (int kh = 0; kh < 2; kh++) {
                int kc = kb + kh*32 + lg*8;
                int kcc = (kc + 8 <= KTOT) ? kc : KTOT - 8;  // clamp (P=0 there)
                bv[nfv][kh] = __builtin_bit_cast(bf16x8,
                    *(const uint4*)(vbase + (size_t)(nfv*16 + l15) * KTOT + kcc));
            }

        #pragma unroll
        for (int rf = 0; rf < 2; rf++) {
            #pragma unroll
            for (int r = 0; r < 4; r++) {
                const int qpos = q0 + rf*16 + lg*4 + r;
                float vals[4];
                float tmax = -INFINITY;
                #pragma unroll
                for (int nf = 0; nf < 4; nf++) {
                    int key = kb + nf*16 + l15;
                    float v = s[rf][nf][r] * sc;
                    int kpos = (key < NBLK) ? key * 64 + 63 : 3024 + key;
                    v = (key < KTOT) ? ((kpos <= qpos) ? v : -1e9f) : -INFINITY;
                    vals[nf] = v;
                    tmax = fmaxf(tmax, v);
                }
                #pragma unroll
                for (int d = 1; d < 16; d <<= 1)
                    tmax = fmaxf(tmax, __shfl_xor(tmax, d));
                float mn = fmaxf(m[rf][r], tmax);
                float scl = __expf(m[rf][r] - mn);
                m[rf][r] = mn;
                float rs = 0.f;
                #pragma unroll
                for (int nf = 0; nf < 4; nf++) {
                    unsigned short pb = f2bf(__expf(vals[nf] - mn));
                    rs += bf2f(pb);          // sum the ROUNDED p: exact convex comb
                    Pl[w][rf*16 + lg*4 + r][nf*16 + l15] = pb;
                }
                #pragma unroll
                for (int d = 1; d < 16; d <<= 1)
                    rs += __shfl_xor(rs, d);
                lrun[rf][r] = lrun[rf][r] * scl + rs;
                #pragma unroll
                for (int nfv = 0; nfv < 4; nfv++)
                    oacc[rf][nfv][r] *= scl;
            }
        }

        #pragma unroll
        for (int rf = 0; rf < 2; rf++) {
            bf16x8 pa[2];
            #pragma unroll
            for (int kh = 0; kh < 2; kh++)
                pa[kh] = __builtin_bit_cast(bf16x8,
                    *(const uint4*)&Pl[w][rf*16 + l15][kh*32 + lg*8]);
            #pragma unroll
            for (int nfv = 0; nfv < 4; nfv++)
                #pragma unroll
                for (int kh = 0; kh < 2; kh++)
                    oacc[rf][nfv] = __builtin_amdgcn_mfma_f32_16x16x32_bf16(
                                        pa[kh], bv[nfv][kh], oacc[rf][nfv], 0, 0, 0);
        }
    }

    #pragma unroll
    for (int rf = 0; rf < 2; rf++) {
        #pragma unroll
        for (int r = 0; r < 4; r++) {
            float inv = 1.f / lrun[rf][r];
            int q = q0 + rf*16 + lg*4 + r;
            size_t obase = ((size_t)(b * T_ + q)) * 1024 + h * 64;
            #pragma unroll
            for (int nfv = 0; nfv < 4; nfv++)
                attn_out[obase + nfv*16 + l15] = f2bf(oacc[rf][nfv][r] * inv);
        }
    }
}

// ---------- host launch ----------
extern "C" void kernel_launch(void* const* d_in, const int* in_sizes, int n_in,
                              void* d_out, int out_size, void* d_ws, size_t ws_size,
                              hipStream_t stream) {
    const float* x      = (const float*)d_in[0];
    const float* Wq_sem = (const float*)d_in[1];
    const float* Wk_sem = (const float*)d_in[2];
    const float* Wq_geo = (const float*)d_in[3];
    const float* Wk_geo = (const float*)d_in[4];
    const float* Wv     = (const float*)d_in[5];
    const float* Wo     = (const float*)d_in[6];
    const float* ls     = (const float*)d_in[7];

    char* w = (char*)d_ws;
    auto alloc = [&](size_t bytes) {
        char* p = w;
        w += (bytes + 255) & ~(size_t)255;
        return p;
    };
    unsigned short* WcatT = (unsigned short*)alloc((size_t)1536 * 2048 * 2);
    unsigned short* WoT   = (unsigned short*)alloc((size_t)2048 * 1024 * 2);
    unsigned short* qcat  = (unsigned short*)alloc((size_t)2 * 16 * 4096 * 64 * 2);
    unsigned short* kp    = (unsigned short*)alloc((size_t)2 * 4 * 1072 * 64 * 2);
    unsigned short* vt    = (unsigned short*)alloc((size_t)2 * 4 * 1072 * 64 * 2);
    unsigned short* aout  = (unsigned short*)alloc((size_t)8192 * 1024 * 2);

    hipFuncSetAttribute(reinterpret_cast<const void*>(&gemmP<0>),
                        hipFuncAttributeMaxDynamicSharedMemorySize, 49152);
    hipFuncSetAttribute(reinterpret_cast<const void*>(&gemmP<1>),
                        hipFuncAttributeMaxDynamicSharedMemorySize, 49152);

    // 1) all weight transposes in ONE launch
    transpose_all<<<5120, dim3(32, 8), 0, stream>>>(
        Wq_sem, Wq_geo, Wk_sem, Wk_geo, Wv, Wo, WcatT, WoT);

    // 2) fused projection GEMM (cvt + RoPE + pooling fused) -> qcat / kp / vt
    gemmP<0><<<768, 256, 49152, stream>>>(
        x, WcatT, nullptr, qcat, kp, vt, 8192, 1536, 2048, 12);

    // 3) wave-independent MFMA flash attention
    attn_fwd<<<dim3(1024), 256, 0, stream>>>(qcat, kp, vt, ls, aout);

    // 4) output projection -> d_out (fp32); ring-3 (R8 config)
    gemmP<1><<<1024, 256, 49152, stream>>>(
        aout, WoT, (float*)d_out, nullptr, nullptr, nullptr, 8192, 2048, 1024, 16);
}

// Round 14
// 179.336 us; speedup vs baseline: 1.1974x; 1.0332x over previous
//
#include <hip/hip_runtime.h>
#include <math.h>

// ---------- constants ----------
#define B_  2
#define T_  4096
#define DM  2048
#define H_  16
#define HKV 4
#define DV_ 64
#define MB_ 64
#define LW_ 1024
#define REMOTE 3072     // T - LW
#define NBLK 48         // REMOTE/MB
#define KTOT 1072       // NBLK + LW
#define NTILES 17       // ceil(1072/64)

typedef __bf16 bf16x8 __attribute__((ext_vector_type(8)));
typedef float  f32x4  __attribute__((ext_vector_type(4)));

__device__ __forceinline__ float bf2f(unsigned short u) {
    unsigned int x = ((unsigned int)u) << 16;
    return __builtin_bit_cast(float, x);
}
__device__ __forceinline__ unsigned short f2bf(float f) {
    unsigned int x = __builtin_bit_cast(unsigned int, f);
    x = x + 0x7fffu + ((x >> 16) & 1u);   // round-to-nearest-even
    return (unsigned short)(x >> 16);
}

// async global->LDS, 16B per lane; LDS dest = wave-uniform base + lane*16
__device__ __forceinline__ void gload16(const void* gsrc, unsigned short* ldst) {
    __builtin_amdgcn_global_load_lds(
        (const __attribute__((address_space(1))) void*)gsrc,
        (__attribute__((address_space(3))) void*)ldst,
        16, 0, 0);
}

// ---------- ALL weight transposes in one launch ----------
__global__ void transpose_all(const float* __restrict__ Wq_sem,
                              const float* __restrict__ Wq_geo,
                              const float* __restrict__ Wk_sem,
                              const float* __restrict__ Wk_geo,
                              const float* __restrict__ Wv,
                              const float* __restrict__ Wo,
                              unsigned short* __restrict__ WcatT,
                              unsigned short* __restrict__ WoT) {
    __shared__ float tile[32][33];
    const int bid = blockIdx.x;
    const float* src; unsigned short* dst; int R, C, tiles_x, lt;
    if (bid < 1024)      { src = Wq_sem; dst = WcatT;                       R = 2048; C = 512;  tiles_x = 16; lt = bid; }
    else if (bid < 2048) { src = Wq_geo; dst = WcatT + (size_t)512  * 2048; R = 2048; C = 512;  tiles_x = 16; lt = bid - 1024; }
    else if (bid < 2304) { src = Wk_sem; dst = WcatT + (size_t)1024 * 2048; R = 2048; C = 128;  tiles_x = 4;  lt = bid - 2048; }
    else if (bid < 2560) { src = Wk_geo; dst = WcatT + (size_t)1152 * 2048; R = 2048; C = 128;  tiles_x = 4;  lt = bid - 2304; }
    else if (bid < 3072) { src = Wv;     dst = WcatT + (size_t)1280 * 2048; R = 2048; C = 256;  tiles_x = 8;  lt = bid - 2560; }
    else                 { src = Wo;     dst = WoT;                         R = 1024; C = 2048; tiles_x = 64; lt = bid - 3072; }
    const int ct = lt % tiles_x, rt = lt / tiles_x;
    const int tx = threadIdx.x, ty = threadIdx.y;
    #pragma unroll
    for (int i = ty; i < 32; i += 8)
        tile[i][tx] = src[(size_t)(rt * 32 + i) * C + ct * 32 + tx];
    __syncthreads();
    #pragma unroll
    for (int i = ty; i < 32; i += 8)
        dst[(size_t)(ct * 32 + i) * R + rt * 32 + tx] = f2bf(tile[tx][i]);
}

// ---------- projection GEMM: 128x128, ring-3, fused cvt+RoPE+pool ----------
// A = x in FP32 (T14 reg-stage: f32 global->regs, cvt, swizzled ds_write one
// iter later, BEFORE the MFMA phase so it hides under it).  B via gload_lds.
// NO explicit vmcnt: writeA's register dep on A(t+1) loads implies (FIFO
// retirement) that B(t+1) and older are retired.  lgkmcnt(0)+barrier per tile.
__global__ __launch_bounds__(256, 3) void gemmProj(
    const float* __restrict__ Axf0,
    const unsigned short* __restrict__ BT,
    unsigned short* __restrict__ qcat,
    unsigned short* __restrict__ kp,    // [bg][key][64]
    unsigned short* __restrict__ vt,    // [bg][d][KTOT]
    int K, int nbx)
{
    extern __shared__ __align__(16) unsigned short lds[];  // 3*8192 ushorts

    const int tid = threadIdx.x;
    const int lane = tid & 63, w = tid >> 6;   // 4 waves: 2x2
    const int wr = w >> 1, wc = w & 1;
    const int l15 = lane & 15, lg = lane >> 4;

    const int cpx = gridDim.x >> 3;
    const int swz = (blockIdx.x & 7) * cpx + (blockIdx.x >> 3);
    const int bx = swz % nbx, by = swz / nbx;
    const int row0 = by * 128, col0 = bx * 128;

    const int scol = ((lane & 3) ^ ((lane >> 3) & 3)) * 8;
    const int srA = w * 16 + (lane >> 2);
    const unsigned short* Bg = BT + (size_t)col0 * K;

    const int ar0 = tid >> 2, ar1 = ar0 + 64, ac = tid & 3;
    const int agc0 = (ac ^ ((ar0 >> 1) & 3)) * 8;
    const int agc1 = (ac ^ ((ar1 >> 1) & 3)) * 8;
    const float* Axf = Axf0 + (size_t)row0 * K;

    const int rdsw = (lg ^ ((l15 >> 1) & 3)) * 8;
    const int aoff = (wr * 64 + l15) * 32 + rdsw;
    const int boff = (wc * 64 + l15) * 32 + rdsw;

    const int NT = K >> 5;
    f32x4 acc[4][4] = {};

    auto stageB = [&](int s, int kk) {
        unsigned short* sb = lds + s * 8192 + 4096;
        #pragma unroll
        for (int j = 0; j < 2; j++)
            gload16(Bg + (size_t)(srA + j * 64) * K + kk + scol,
                    sb + (j * 256 + w * 64) * 8);
    };
    auto issueA = [&](float4* ra, int kk) {
        ra[0] = *(const float4*)&Axf[(size_t)ar0 * K + kk + agc0];
        ra[1] = *(const float4*)&Axf[(size_t)ar0 * K + kk + agc0 + 4];
        ra[2] = *(const float4*)&Axf[(size_t)ar1 * K + kk + agc1];
        ra[3] = *(const float4*)&Axf[(size_t)ar1 * K + kk + agc1 + 4];
    };
    auto writeA = [&](int s, const float4* ra) {
        unsigned short* sa = lds + s * 8192;
        bf16x8 v0, v1;
        v0[0] = (__bf16)ra[0].x; v0[1] = (__bf16)ra[0].y;
        v0[2] = (__bf16)ra[0].z; v0[3] = (__bf16)ra[0].w;
        v0[4] = (__bf16)ra[1].x; v0[5] = (__bf16)ra[1].y;
        v0[6] = (__bf16)ra[1].z; v0[7] = (__bf16)ra[1].w;
        v1[0] = (__bf16)ra[2].x; v1[1] = (__bf16)ra[2].y;
        v1[2] = (__bf16)ra[2].z; v1[3] = (__bf16)ra[2].w;
        v1[4] = (__bf16)ra[3].x; v1[5] = (__bf16)ra[3].y;
        v1[6] = (__bf16)ra[3].z; v1[7] = (__bf16)ra[3].w;
        *(uint4*)&sa[ar0 * 32 + ac * 8] = __builtin_bit_cast(uint4, v0);
        *(uint4*)&sa[ar1 * 32 + ac * 8] = __builtin_bit_cast(uint4, v1);
    };
    auto mfmaTile = [&](int rs_) {
        const unsigned short* As_ = lds + rs_ * 8192;
        const unsigned short* Bs_ = As_ + 4096;
        bf16x8 af[4], bfr[4];
        #pragma unroll
        for (int mf = 0; mf < 4; mf++)
            af[mf] = __builtin_bit_cast(bf16x8, *(const uint4*)&As_[aoff + mf * 512]);
        #pragma unroll
        for (int nf = 0; nf < 4; nf++)
            bfr[nf] = __builtin_bit_cast(bf16x8, *(const uint4*)&Bs_[boff + nf * 512]);
        __builtin_amdgcn_s_setprio(1);
        #pragma unroll
        for (int mf = 0; mf < 4; mf++)
            #pragma unroll
            for (int nf = 0; nf < 4; nf++)
                acc[mf][nf] = __builtin_amdgcn_mfma_f32_16x16x32_bf16(
                    af[mf], bfr[nf], acc[mf][nf], 0, 0, 0);
        __builtin_amdgcn_s_setprio(0);
    };

    // prologue: B(0),B(1) async; A(0),A(1) -> regs; write A(0)
    stageB(0, 0);
    stageB(1, 32);
    __builtin_amdgcn_sched_barrier(0);
    float4 rA[4], rB[4];
    issueA(rA, 0);
    issueA(rB, 32);
    writeA(0, rA);                 // waits A(0) => B(0),B(1) retired (FIFO)
    asm volatile("s_waitcnt lgkmcnt(0)" ::: "memory");
    __builtin_amdgcn_s_barrier();

    int rs = 0;
    for (int t = 0; t < NT; t += 2) {
        const int s1 = (rs == 2) ? 0 : rs + 1;
        const int s2 = (s1 == 2) ? 0 : s1 + 1;
        // ---- even: tile t (slot rs) ----
        if (t + 2 < NT) {
            stageB(s2, (t + 2) << 5);
            __builtin_amdgcn_sched_barrier(0);   // keep B-before-A FIFO order
            issueA(rA, (t + 2) << 5);
        }
        writeA(s1, rB);            // tile t+1; implicit wait retires B(t+1)
        mfmaTile(rs);
        asm volatile("s_waitcnt lgkmcnt(0)" ::: "memory");
        __builtin_amdgcn_s_barrier();
        // ---- odd: tile t+1 (slot s1) ----
        if (t + 3 < NT) {
            stageB(rs, (t + 3) << 5);
            __builtin_amdgcn_sched_barrier(0);
            issueA(rB, (t + 3) << 5);
        }
        if (t + 2 < NT) writeA(s2, rA);   // tile t+2
        mfmaTile(s1);
        asm volatile("s_waitcnt lgkmcnt(0)" ::: "memory");
        __builtin_amdgcn_s_barrier();
        rs = s2;
    }

    // ---- fused epilogue (validated since R8) ----
    const int cspan = col0 + wc * 64;
    const int tbase = row0 & 4095;
    const int bq = row0 >> 12;

    if ((cspan >= 512 && cspan < 1024) || (cspan >= 1152 && cspan < 1280)) {
        const float invf = exp2f(-(float)l15 * 0.8304820237218406f);
        #pragma unroll
        for (int mf = 0; mf < 4; mf++) {
            #pragma unroll
            for (int r = 0; r < 4; r++) {
                float s, c;
                sincosf((float)(tbase + wr*64 + mf*16 + lg*4 + r) * invf, &s, &c);
                float a0 = acc[mf][0][r], a1 = acc[mf][1][r];
                acc[mf][0][r] = a0 * c - a1 * s;
                acc[mf][1][r] = a1 * c + a0 * s;
                float a2 = acc[mf][2][r], a3 = acc[mf][3][r];
                acc[mf][2][r] = a2 * c - a3 * s;
                acc[mf][3][r] = a3 * c + a2 * s;
            }
        }
    }

    if (cspan < 1024) {
        #pragma unroll
        for (int nf = 0; nf < 4; nf++) {
            int col = cspan + nf * 16 + l15;
            int h = (col < 512) ? (col >> 5) : ((col - 512) >> 5);
            int d = (col < 512) ? (col & 31) : (32 + (col & 31));
            unsigned short* qb =
                qcat + (((size_t)(bq * 16 + h)) * 4096 + tbase) * 64 + d;
            #pragma unroll
            for (int mf = 0; mf < 4; mf++)
                #pragma unroll
                for (int r = 0; r < 4; r++)
                    qb[(size_t)(wr*64 + mf*16 + lg*4 + r) * 64] =
                        f2bf(acc[mf][nf][r]);
        }
    } else if (tbase >= REMOTE) {
        #pragma unroll
        for (int nf = 0; nf < 4; nf++) {
            int col = cspan + nf * 16 + l15;
            #pragma unroll
            for (int mf = 0; mf < 4; mf++)
                #pragma unroll
                for (int r = 0; r < 4; r++) {
                    int key = tbase + wr*64 + mf*16 + lg*4 + r - 3024;
                    unsigned short hv = f2bf(acc[mf][nf][r]);
                    if (col < 1280) {
                        int g, dk;
                        if (col < 1152) { g = (col - 1024) >> 5; dk = col & 31; }
                        else            { g = (col - 1152) >> 5; dk = 32 + (col & 31); }
                        kp[(((size_t)(bq*4 + g)) * KTOT + key) * 64 + dk] = hv;
                    } else {
                        int g = (col - 1280) >> 6, dv = col & 63;
                        vt[(((size_t)(bq*4 + g)) * 64 + dv) * KTOT + key] = hv;
                    }
                }
        }
    } else {
        #pragma unroll
        for (int nf = 0; nf < 4; nf++) {
            float ps = 0.f;
            #pragma unroll
            for (int mf = 0; mf < 4; mf++)
                #pragma unroll
                for (int r = 0; r < 4; r++) ps += acc[mf][nf][r];
            ps += __shfl_xor(ps, 16);
            ps += __shfl_xor(ps, 32);
            if (lane < 16) {
                int col = cspan + nf * 16 + l15;
                int key = (tbase >> 6) + wr;
                unsigned short hv = f2bf(ps * (1.f / 64.f));
                if (col < 1280) {
                    int g, dk;
                    if (col < 1152) { g = (col - 1024) >> 5; dk = col & 31; }
                    else            { g = (col - 1152) >> 5; dk = 32 + (col & 31); }
                    kp[(((size_t)(bq*4 + g)) * KTOT + key) * 64 + dk] = hv;
                } else {
                    int g = (col - 1280) >> 6, dv = col & 63;
                    vt[(((size_t)(bq*4 + g)) * 64 + dv) * KTOT + key] = hv;
                }
            }
        }
    }
}

// ---------- Wo GEMM: 128x256 tile, ring-3, counted vmcnt(6) ----------------
// 512 blocks = 2/CU single round.  4 waves 1x4 (wave w -> cols w*64),
// acc[8][4] = 32 MFMA/tile/wave.  Slot = A(8KB) + B(16KB) = 24KB; ring-3 72KB.
__global__ __launch_bounds__(256, 2) void gemmWo(
    const unsigned short* __restrict__ A,
    const unsigned short* __restrict__ BT,
    float* __restrict__ outF,
    int N, int K, int nbx)
{
    extern __shared__ __align__(16) unsigned short lds[];  // 3*12288 ushorts

    const int tid = threadIdx.x;
    const int lane = tid & 63, w = tid >> 6;
    const int l15 = lane & 15, lg = lane >> 4;

    const int cpx = gridDim.x >> 3;
    const int swz = (blockIdx.x & 7) * cpx + (blockIdx.x >> 3);
    const int bx = swz % nbx, by = swz / nbx;
    const int row0 = by * 128, col0 = bx * 256;

    const int scol = ((lane & 3) ^ ((lane >> 3) & 3)) * 8;
    const int srA = w * 16 + (lane >> 2);           // + j*64
    const unsigned short* Ag = A  + (size_t)row0 * K;
    const unsigned short* Bg = BT + (size_t)col0 * K;

    const int rdsw = (lg ^ ((l15 >> 1) & 3)) * 8;
    const int aoff = l15 * 32 + rdsw;               // + mf*512, mf 0..7
    const int boff = (w * 64 + l15) * 32 + rdsw;    // + nf*512

    const int NT = K >> 5;
    f32x4 acc[8][4] = {};

    auto stage = [&](int s, int kk) {
        unsigned short* sa = lds + s * 12288;
        unsigned short* sb = sa + 4096;
        #pragma unroll
        for (int j = 0; j < 2; j++)                 // A: 128 rows
            gload16(Ag + (size_t)(srA + j * 64) * K + kk + scol,
                    sa + (j * 256 + w * 64) * 8);
        #pragma unroll
        for (int j = 0; j < 4; j++)                 // B: 256 rows
            gload16(Bg + (size_t)(srA + j * 64) * K + kk + scol,
                    sb + (j * 256 + w * 64) * 8);
    };

    stage(0, 0);
    stage(1, 32);
    asm volatile("s_waitcnt vmcnt(6)" ::: "memory");   // tile0 landed

    int rs = 0;
    for (int t = 0; t < NT; ++t) {
        __builtin_amdgcn_s_barrier();
        if (t + 2 < NT) stage(rs == 0 ? 2 : rs - 1, (t + 2) << 5);

        const unsigned short* As_ = lds + rs * 12288;
        const unsigned short* Bs_ = As_ + 4096;
        bf16x8 af[8], bfr[4];
        #pragma unroll
        for (int mf = 0; mf < 8; mf++)
            af[mf] = __builtin_bit_cast(bf16x8, *(const uint4*)&As_[aoff + mf * 512]);
        #pragma unroll
        for (int nf = 0; nf < 4; nf++)
            bfr[nf] = __builtin_bit_cast(bf16x8, *(const uint4*)&Bs_[boff + nf * 512]);

        __builtin_amdgcn_s_setprio(1);
        #pragma unroll
        for (int mf = 0; mf < 8; mf++)
            #pragma unroll
            for (int nf = 0; nf < 4; nf++)
                acc[mf][nf] = __builtin_amdgcn_mfma_f32_16x16x32_bf16(
                                  af[mf], bfr[nf], acc[mf][nf], 0, 0, 0);
        __builtin_amdgcn_s_setprio(0);

        if (t + 2 < NT) asm volatile("s_waitcnt vmcnt(6)" ::: "memory");
        else            asm volatile("s_waitcnt vmcnt(0)" ::: "memory");
        rs = (rs == 2) ? 0 : rs + 1;
    }

    #pragma unroll
    for (int mf = 0; mf < 8; mf++)
        #pragma unroll
        for (int nf = 0; nf < 4; nf++)
            #pragma unroll
            for (int r = 0; r < 4; r++) {
                int row = row0 + mf * 16 + lg * 4 + r;
                int col = col0 + w * 64 + nf * 16 + l15;
                outF[(size_t)row * N + col] = acc[mf][nf][r];
            }
}

// ---------- MFMA flash attention, wave-independent (NO barriers) ----------
__global__ __launch_bounds__(256) void attn_fwd(
    const unsigned short* __restrict__ qcat,
    const unsigned short* __restrict__ kp,   // [bg][key][64]
    const unsigned short* __restrict__ vt,   // [bg][d][KTOT]
    const float* __restrict__ ls,
    unsigned short* __restrict__ attn_out)
{
    __shared__ unsigned short Pl[4][32][72];   // per-wave P tile (bf16)

    const int tid = threadIdx.x;
    const int lane = tid & 63, w = tid >> 6;
    const int l15 = lane & 15, lg = lane >> 4;

    const int wid = blockIdx.x * 4 + w;        // 0..4095
    const int hb = wid & 31;
    const int iu = wid >> 5;                   // schedule slot 0..127
    int i;
    if (iu < 32)       i = 127 - iu;
    else if (iu == 32) i = 0;
    else if (iu == 33) i = 1;
    else               i = iu - 32;
    const int h = hb & 15, b = hb >> 4, g = h >> 2;
    const int q0 = i * 32;

    int ktmax;
    if (q0 < 64) ktmax = NTILES;               // uniform rows: all keys
    else {
        int lastkey = q0 + 31 - 3024;          // max valid local key index
        ktmax = (lastkey < NBLK) ? 1 : (lastkey / 64 + 1);
    }

    const float sc = __expf(ls[h]) * 0.17677669529663687f;   // exp(ls)/sqrt(32)

    bf16x8 aq[2][2];
    const unsigned short* qbase = qcat + (((size_t)(b * 16 + h)) * T_ + q0) * 64;
    #pragma unroll
    for (int rf = 0; rf < 2; rf++)
        #pragma unroll
        for (int kh = 0; kh < 2; kh++)
            aq[rf][kh] = __builtin_bit_cast(bf16x8,
                *(const uint4*)(qbase + (size_t)(rf*16 + l15)*64 + kh*32 + lg*8));

    float m[2][4], lrun[2][4];
    #pragma unroll
    for (int rf = 0; rf < 2; rf++)
        #pragma unroll
        for (int r = 0; r < 4; r++) { m[rf][r] = -1e9f; lrun[rf][r] = 0.f; }
    f32x4 oacc[2][4] = {};

    const unsigned short* kbase = kp + ((size_t)(b * 4 + g)) * KTOT * 64;
    const unsigned short* vbase = vt + ((size_t)(b * 4 + g)) * 64 * KTOT;

    for (int kt = 0; kt < ktmax; kt++) {
        const int kb = kt * 64;

        bf16x8 bk[4][2];
        #pragma unroll
        for (int nf = 0; nf < 4; nf++) {
            int krow = kb + nf*16 + l15;
            int krc = krow < KTOT ? krow : KTOT - 1;     // clamp (masked later)
            #pragma unroll
            for (int kh = 0; kh < 2; kh++)
                bk[nf][kh] = __builtin_bit_cast(bf16x8,
                    *(const uint4*)(kbase + (size_t)krc * 64 + kh*32 + lg*8));
        }

        f32x4 s[2][4] = {};
        #pragma unroll
        for (int rf = 0; rf < 2; rf++)
            #pragma unroll
            for (int nf = 0; nf < 4; nf++)
                #pragma unroll
                for (int kh = 0; kh < 2; kh++)
                    s[rf][nf] = __builtin_amdgcn_mfma_f32_16x16x32_bf16(
                                    aq[rf][kh], bk[nf][kh], s[rf][nf], 0, 0, 0);

        bf16x8 bv[4][2];
        #pragma unroll
        for (int nfv = 0; nfv < 4; nfv++)
            #pragma unroll
            for (int kh = 0; kh < 2; kh++) {
                int kc = kb + kh*32 + lg*8;
                int kcc = (kc + 8 <= KTOT) ? kc : KTOT - 8;  // clamp (P=0 there)
                bv[nfv][kh] = __builtin_bit_cast(bf16x8,
                    *(const uint4*)(vbase + (size_t)(nfv*16 + l15) * KTOT + kcc));
            }

        #pragma unroll
        for (int rf = 0; rf < 2; rf++) {
            #pragma unroll
            for (int r = 0; r < 4; r++) {
                const int qpos = q0 + rf*16 + lg*4 + r;
                float vals[4];
                float tmax = -INFINITY;
                #pragma unroll
                for (int nf = 0; nf < 4; nf++) {
                    int key = kb + nf*16 + l15;
                    float v = s[rf][nf][r] * sc;
                    int kpos = (key < NBLK) ? key * 64 + 63 : 3024 + key;
                    v = (key < KTOT) ? ((kpos <= qpos) ? v : -1e9f) : -INFINITY;
                    vals[nf] = v;
                    tmax = fmaxf(tmax, v);
                }
                #pragma unroll
                for (int d = 1; d < 16; d <<= 1)
                    tmax = fmaxf(tmax, __shfl_xor(tmax, d));
                float mn = fmaxf(m[rf][r], tmax);
                float scl = __expf(m[rf][r] - mn);
                m[rf][r] = mn;
                float rs = 0.f;
                #pragma unroll
                for (int nf = 0; nf < 4; nf++) {
                    unsigned short pb = f2bf(__expf(vals[nf] - mn));
                    rs += bf2f(pb);          // sum the ROUNDED p: exact convex comb
                    Pl[w][rf*16 + lg*4 + r][nf*16 + l15] = pb;
                }
                #pragma unroll
                for (int d = 1; d < 16; d <<= 1)
                    rs += __shfl_xor(rs, d);
                lrun[rf][r] = lrun[rf][r] * scl + rs;
                #pragma unroll
                for (int nfv = 0; nfv < 4; nfv++)
                    oacc[rf][nfv][r] *= scl;
            }
        }

        #pragma unroll
        for (int rf = 0; rf < 2; rf++) {
            bf16x8 pa[2];
            #pragma unroll
            for (int kh = 0; kh < 2; kh++)
                pa[kh] = __builtin_bit_cast(bf16x8,
                    *(const uint4*)&Pl[w][rf*16 + l15][kh*32 + lg*8]);
            #pragma unroll
            for (int nfv = 0; nfv < 4; nfv++)
                #pragma unroll
                for (int kh = 0; kh < 2; kh++)
                    oacc[rf][nfv] = __builtin_amdgcn_mfma_f32_16x16x32_bf16(
                                        pa[kh], bv[nfv][kh], oacc[rf][nfv], 0, 0, 0);
        }
    }

    #pragma unroll
    for (int rf = 0; rf < 2; rf++) {
        #pragma unroll
        for (int r = 0; r < 4; r++) {
            float inv = 1.f / lrun[rf][r];
            int q = q0 + rf*16 + lg*4 + r;
            size_t obase = ((size_t)(b * T_ + q)) * 1024 + h * 64;
            #pragma unroll
            for (int nfv = 0; nfv < 4; nfv++)
                attn_out[obase + nfv*16 + l15] = f2bf(oacc[rf][nfv][r] * inv);
        }
    }
}

// ---------- host launch ----------
extern "C" void kernel_launch(void* const* d_in, const int* in_sizes, int n_in,
                              void* d_out, int out_size, void* d_ws, size_t ws_size,
                              hipStream_t stream) {
    const float* x      = (const float*)d_in[0];
    const float* Wq_sem = (const float*)d_in[1];
    const float* Wk_sem = (const float*)d_in[2];
    const float* Wq_geo = (const float*)d_in[3];
    const float* Wk_geo = (const float*)d_in[4];
    const float* Wv     = (const float*)d_in[5];
    const float* Wo     = (const float*)d_in[6];
    const float* ls     = (const float*)d_in[7];

    char* w = (char*)d_ws;
    auto alloc = [&](size_t bytes) {
        char* p = w;
        w += (bytes + 255) & ~(size_t)255;
        return p;
    };
    unsigned short* WcatT = (unsigned short*)alloc((size_t)1536 * 2048 * 2);
    unsigned short* WoT   = (unsigned short*)alloc((size_t)2048 * 1024 * 2);
    unsigned short* qcat  = (unsigned short*)alloc((size_t)2 * 16 * 4096 * 64 * 2);
    unsigned short* kp    = (unsigned short*)alloc((size_t)2 * 4 * 1072 * 64 * 2);
    unsigned short* vt    = (unsigned short*)alloc((size_t)2 * 4 * 1072 * 64 * 2);
    unsigned short* aout  = (unsigned short*)alloc((size_t)8192 * 1024 * 2);

    hipFuncSetAttribute(reinterpret_cast<const void*>(&gemmProj),
                        hipFuncAttributeMaxDynamicSharedMemorySize, 49152);
    hipFuncSetAttribute(reinterpret_cast<const void*>(&gemmWo),
                        hipFuncAttributeMaxDynamicSharedMemorySize, 73728);

    // 1) all weight transposes in ONE launch
    transpose_all<<<5120, dim3(32, 8), 0, stream>>>(
        Wq_sem, Wq_geo, Wk_sem, Wk_geo, Wv, Wo, WcatT, WoT);

    // 2) fused projection GEMM (cvt + RoPE + pooling) -> qcat / kp / vt
    gemmProj<<<768, 256, 49152, stream>>>(
        x, WcatT, qcat, kp, vt, 2048, 12);

    // 3) wave-independent MFMA flash attention
    attn_fwd<<<dim3(1024), 256, 0, stream>>>(qcat, kp, vt, ls, aout);

    // 4) output projection -> d_out (fp32); 128x256 tile, 512 blocks @ 2/CU
    gemmWo<<<512, 256, 73728, stream>>>(
        aout, WoT, (float*)d_out, 2048, 1024, 8);
}